// Round 11
// baseline (955.060 us; speedup 1.0000x reference)
//
#include <hip/hip_runtime.h>
#include <hip/hip_bf16.h>
#include <cstdint>

#define B_   2
#define S_   2048
#define D_   4096
#define NH_  32
#define NKV_ 8
#define HD_  128
#define BS_  (B_*S_)      // 4096 rows
#define NQK_ 6144         // NH*HD + 2*NKV*HD

typedef __bf16 bf16_t;
typedef __bf16 bf16x8 __attribute__((ext_vector_type(8)));
typedef __bf16 bf16x4 __attribute__((ext_vector_type(4)));
typedef __bf16 bf16x2 __attribute__((ext_vector_type(2)));
typedef float  f32x4  __attribute__((ext_vector_type(4)));
typedef unsigned uint32x4 __attribute__((ext_vector_type(4)));

typedef const __attribute__((address_space(1))) void* gas_ptr;
typedef __attribute__((address_space(3))) void* las_ptr;

__device__ __forceinline__ void gload_lds16(const void* g, void* l) {
  __builtin_amdgcn_global_load_lds((gas_ptr)g, (las_ptr)l, 16, 0, 0);
}

__device__ __forceinline__ float exp2_fast(float x) {   // v_exp_f32 = 2^x
  float r;
  asm("v_exp_f32 %0, %1" : "=v"(r) : "v"(x));
  return r;
}

__device__ __forceinline__ unsigned cvt_pk_bf16(float a, float b) {
  unsigned r;
  asm("v_cvt_pk_bf16_f32 %0, %1, %2" : "=v"(r) : "v"(a), "v"(b));
  return r;
}

#define LD8(p) (*(const bf16x8*)(p))
#define MFMA(a, b, c) __builtin_amdgcn_mfma_f32_16x16x32_bf16(a, b, c, 0, 0, 0)

// ---------------- f32 -> bf16 convert (vectorized) ----------------
__global__ __launch_bounds__(256) void k_cvt(const float4* __restrict__ in,
                                             bf16x4* __restrict__ out, int n4) {
  int i = blockIdx.x * 256 + threadIdx.x;
  if (i >= n4) return;
  float4 v = in[i];
  bf16x4 o = { (bf16_t)v.x, (bf16_t)v.y, (bf16_t)v.z, (bf16_t)v.w };
  out[i] = o;
}

// ---------------- w[K][N] f32 -> wt[N][K] bf16 (tiled transpose) ----------------
__global__ __launch_bounds__(256) void k_transpose_cvt(const float* __restrict__ w,
                                                       bf16_t* __restrict__ wt,
                                                       int K, int N) {
  __shared__ float tile[32][33];
  int n0 = blockIdx.x * 32, k0 = blockIdx.y * 32;
  int tx = threadIdx.x, ty = threadIdx.y;   // 32x8
#pragma unroll
  for (int i = 0; i < 4; i++)
    tile[ty + 8*i][tx] = w[(size_t)(k0 + ty + 8*i) * N + n0 + tx];
  __syncthreads();
#pragma unroll
  for (int i = 0; i < 4; i++)
    wt[(size_t)(n0 + ty + 8*i) * K + k0 + tx] = (bf16_t)tile[tx][ty + 8*i];
}

// ---------------- 256x(64*NF) NT GEMM — 4-phase/K-tile template ----------------
// NF=3 for QKV (512 blocks = 2 clean rounds), NF=4 for out-proj (256 = 1 round).
template <typename CT, int NF>
__global__ __launch_bounds__(512, 2) void k_gemm8p(const bf16_t* __restrict__ A,
                                                   const bf16_t* __restrict__ Bt,
                                                   CT* __restrict__ C,
                                                   int M, int N, int K) {
  __shared__ __align__(16) bf16_t As[2][256 * 64];       // 2 x 32 KB
  __shared__ __align__(16) bf16_t Bs[2][NF * 64 * 64];   // 2 x 8NF KB
  const int tid = threadIdx.x;
  const int l = tid & 63, w = tid >> 6;
  const int lr = l & 15, lg = l >> 4;
  const int wm = w >> 2, wn = w & 3;       // 2M x 4N wave grid

  const int bm = blockIdx.x, bn = blockIdx.y;

  const bf16_t* Ab = A  + (size_t)bm * 256 * K;
  const bf16_t* Bb = Bt + (size_t)bn * (NF * 64) * K;

  int st_row[4], st_col[4], st_dst[4];
#pragma unroll
  for (int j = 0; j < 4; j++) {
    int o = (j * 512 + tid) * 16;          // byte offset
    int row = o >> 7, cb = o & 127;        // 128B rows
    st_row[j] = row;
    st_col[j] = (cb ^ ((row & 7) << 4)) >> 1;
    st_dst[j] = o >> 1;
  }

  int aoff[8], boff[NF];
#pragma unroll
  for (int m = 0; m < 8; m++) {
    int r = wm * 128 + m * 16 + lr;
    aoff[m] = r * 64 + (((lg * 16) ^ ((r & 7) << 4)) >> 1);
  }
#pragma unroll
  for (int n = 0; n < NF; n++) {
    int r = wn * (16 * NF) + n * 16 + lr;
    boff[n] = r * 64 + (((lg * 16) ^ ((r & 7) << 4)) >> 1);
  }

  f32x4 acc[8][NF];
#pragma unroll
  for (int m = 0; m < 8; m++)
#pragma unroll
    for (int n = 0; n < NF; n++) acc[m][n] = f32x4{0.f, 0.f, 0.f, 0.f};

  auto stageA = [&](int k, int h) {       // half h: 128 rows, 2 loads
    const int kt = k << 6;
    const int rof = h << 7;
#pragma unroll
    for (int j = 0; j < 2; j++)
      gload_lds16(Ab + (size_t)(st_row[j] + rof) * K + kt + st_col[j],
                  &As[k & 1][0] + (rof << 6) + st_dst[j]);
  };
  auto stageB = [&](int k) {              // full B tile: 64NF rows, NF loads
    const int kt = k << 6;
#pragma unroll
    for (int j = 0; j < NF; j++)
      gload_lds16(Bb + (size_t)st_row[j] * K + kt + st_col[j],
                  &Bs[k & 1][0] + st_dst[j]);
  };

  const int NT = K >> 6;
  stageA(0, 0); stageA(0, 1); stageB(0); stageB(1);
  if constexpr (NF == 3) asm volatile("s_waitcnt vmcnt(3)" ::: "memory");
  else                   asm volatile("s_waitcnt vmcnt(4)" ::: "memory");
  __builtin_amdgcn_s_barrier();

  for (int k = 0; k < NT; ++k) {
    const bf16_t* Ap = &As[k & 1][0];
    const bf16_t* Bp = &Bs[k & 1][0];
    const bool s1 = (k + 1 < NT), s2 = (k + 2 < NT);
    bf16x8 bfr[NF], a[4];

    // ---- P0: b kk0 + a[0..3] kk0 ; stage A-half0(k+1) ----
#pragma unroll
    for (int n = 0; n < NF; n++) bfr[n] = LD8(Bp + boff[n]);
#pragma unroll
    for (int m = 0; m < 4; m++) a[m] = LD8(Ap + aoff[m]);
    if (s1) stageA(k + 1, 0);
    __builtin_amdgcn_s_barrier();
    asm volatile("s_waitcnt lgkmcnt(0)" ::: "memory");
    __builtin_amdgcn_s_setprio(1);
#pragma unroll
    for (int m = 0; m < 4; m++)
#pragma unroll
      for (int n = 0; n < NF; n++)
        acc[m][n] = MFMA(a[m], bfr[n], acc[m][n]);
    __builtin_amdgcn_s_setprio(0);
    __builtin_amdgcn_s_barrier();

    // ---- P1: a[4..7] kk0 ; stage A-half1(k+1) ----
#pragma unroll
    for (int m = 0; m < 4; m++) a[m] = LD8(Ap + aoff[m + 4]);
    if (s1) stageA(k + 1, 1);
    __builtin_amdgcn_s_barrier();
    asm volatile("s_waitcnt lgkmcnt(0)" ::: "memory");
    __builtin_amdgcn_s_setprio(1);
#pragma unroll
    for (int m = 0; m < 4; m++)
#pragma unroll
      for (int n = 0; n < NF; n++)
        acc[m + 4][n] = MFMA(a[m], bfr[n], acc[m + 4][n]);
    __builtin_amdgcn_s_setprio(0);
    __builtin_amdgcn_s_barrier();

    // ---- P2: b kk1 + a[0..3] kk1 ----
#pragma unroll
    for (int n = 0; n < NF; n++) bfr[n] = LD8(Bp + (boff[n] ^ 32));
#pragma unroll
    for (int m = 0; m < 4; m++) a[m] = LD8(Ap + (aoff[m] ^ 32));
    __builtin_amdgcn_s_barrier();
    asm volatile("s_waitcnt lgkmcnt(0)" ::: "memory");
    __builtin_amdgcn_s_setprio(1);
#pragma unroll
    for (int m = 0; m < 4; m++)
#pragma unroll
      for (int n = 0; n < NF; n++)
        acc[m][n] = MFMA(a[m], bfr[n], acc[m][n]);
    __builtin_amdgcn_s_setprio(0);
    __builtin_amdgcn_s_barrier();

    // ---- P3: a[4..7] kk1 ; stage B(k+2) ; boundary vmcnt ----
#pragma unroll
    for (int m = 0; m < 4; m++) a[m] = LD8(Ap + (aoff[m + 4] ^ 32));
    if (s2) {
      stageB(k + 2);
      if constexpr (NF == 3) asm volatile("s_waitcnt vmcnt(3)" ::: "memory");
      else                   asm volatile("s_waitcnt vmcnt(4)" ::: "memory");
    } else if (s1) {
      asm volatile("s_waitcnt vmcnt(0)" ::: "memory");
    }
    __builtin_amdgcn_s_barrier();
    asm volatile("s_waitcnt lgkmcnt(0)" ::: "memory");
    __builtin_amdgcn_s_setprio(1);
#pragma unroll
    for (int m = 0; m < 4; m++)
#pragma unroll
      for (int n = 0; n < NF; n++)
        acc[m + 4][n] = MFMA(a[m], bfr[n], acc[m + 4][n]);
    __builtin_amdgcn_s_setprio(0);
    __builtin_amdgcn_s_barrier();
  }

#pragma unroll
  for (int m = 0; m < 8; m++) {
    int row0 = bm * 256 + wm * 128 + m * 16 + lg * 4;
#pragma unroll
    for (int n = 0; n < NF; n++) {
      int col = bn * (NF * 64) + wn * (16 * NF) + n * 16 + lr;
#pragma unroll
      for (int i = 0; i < 4; i++)
        C[(size_t)(row0 + i) * N + col] = (CT)acc[m][n][i];
    }
  }
}

// ---------------- RoPE + head-major reorder ----------------
__global__ __launch_bounds__(256) void k_rope(const bf16_t* __restrict__ qkv,
                                              const float* __restrict__ fcos,
                                              const float* __restrict__ fsin,
                                              bf16_t* __restrict__ dst,
                                              int nheads, int col_off, float mul) {
  int idx = blockIdx.x * 256 + threadIdx.x;   // B*S*nheads*64 threads
  int p = idx & 63;
  int h = (idx >> 6) % nheads;
  int bs = idx / (64 * nheads);
  int s = bs & (S_ - 1);
  int b = bs >> 11;                            // bs / S_
  const bf16_t* src = qkv + (size_t)bs * NQK_ + col_off + h * HD_ + 2 * p;
  bf16x2 ab = *(const bf16x2*)src;
  float a = (float)ab[0], bb = (float)ab[1];
  float c = fcos[s * 64 + p], sn = fsin[s * 64 + p];
  bf16x2 o = { (bf16_t)((a * c - bb * sn) * mul), (bf16_t)((a * sn + bb * c) * mul) };
  *(bf16x2*)(dst + ((((size_t)b * nheads + h) * S_ + s) * HD_) + 2 * p) = o;
}

// ---------------- V transpose: qkv v-cols -> vt[B][NKV][HD][S] ----------------
__global__ __launch_bounds__(256) void k_vtrans(const bf16_t* __restrict__ qkv,
                                                bf16_t* __restrict__ vtr) {
  __shared__ bf16_t tile[32][33];
  int s0 = blockIdx.x * 32, d0 = blockIdx.y * 32, z = blockIdx.z;  // z = b*NKV+kvh
  int b = z >> 3, kvh = z & 7;
  int tx = threadIdx.x, ty = threadIdx.y;
#pragma unroll
  for (int i = 0; i < 4; i++)
    tile[ty + 8*i][tx] =
        qkv[(size_t)(b * S_ + s0 + ty + 8*i) * NQK_ + (D_ + NKV_ * HD_) + kvh * HD_ + d0 + tx];
  __syncthreads();
#pragma unroll
  for (int i = 0; i < 4; i++)
    vtr[((size_t)z * HD_ + d0 + ty + 8*i) * S_ + s0 + tx] = tile[tx][ty + 8*i];
}

// ---------------- Flash attention (non-causal, GQA) ----------------
// grid (S/256, NH, B), 512 thr (8 waves). Wave w owns q rows [qb*256+w*32, +32).
// Same K/V LDS (64 KB) now shared by 8 waves -> 2 blocks/CU = 16 waves/CU
// (4/SIMD), double round-10's TLP; per-CU staging traffic halves. Swapped QK^T
// (T12) in-register softmax, log2 domain, ones-column row-sum — unchanged.
#define KVBLK 64
#define SM_THR 12.0f     // log2-domain defer threshold (P bounded by 2^12)
__global__ __launch_bounds__(512, 4) void k_flash(const bf16_t* __restrict__ qr,
                                                  const bf16_t* __restrict__ kr,
                                                  const bf16_t* __restrict__ vt,
                                                  bf16_t* __restrict__ ctx) {
  __shared__ __align__(16) bf16_t Ks[2][KVBLK * HD_];   // 2 x 16 KB [row s][col d]
  __shared__ __align__(16) bf16_t Vs[2][HD_ * KVBLK];   // 2 x 16 KB [row d][col s]
  const int tid = threadIdx.x;
  const int l = tid & 63, w = tid >> 6;                 // 8 waves
  const int lr = l & 15, lg = l >> 4;
  const int qb = blockIdx.x, h = blockIdx.y, b = blockIdx.z;
  const int kvh = h >> 2;   // NREP=4

  const bf16_t* qbase = qr + (((size_t)b * NH_ + h) * S_ + qb * 256 + w * 32) * HD_;
  const bf16_t* kbase = kr + (((size_t)b * NKV_ + kvh) * S_) * HD_;
  const bf16_t* vbase = vt + (((size_t)b * NKV_ + kvh) * HD_) * S_;

  // bpermute byte addrs: src lane = lr + 32*(lg&1) (+16 for t>=2)
  const int sl0 = (lr + ((lg & 1) << 5)) << 2;
  const int sl1 = sl0 + (16 << 2);

  // Q fragments (pre-scaled by log2e/sqrt(HD) in k_rope)
  bf16x8 qf[2][4];
#pragma unroll
  for (int m = 0; m < 2; m++)
#pragma unroll
    for (int kk = 0; kk < 4; kk++)
      qf[m][kk] = *(const bf16x8*)(qbase + (m * 16 + lr) * HD_ + kk * 32 + lg * 8);

  bf16x8 ones;
#pragma unroll
  for (int j = 0; j < 8; j++) ones[j] = (bf16_t)1.0f;

  f32x4 o[2][9];                     // [..][8] = row-sum accumulator
#pragma unroll
  for (int m = 0; m < 2; m++)
#pragma unroll
    for (int n = 0; n < 9; n++) o[m][n] = f32x4{0.f, 0.f, 0.f, 0.f};
  float mR[2] = {-1e30f, -1e30f};    // per-lane scalar: lane's q = m*16+lr

  // stage tile t into buffer bu (K: 16KB, V: 16KB; 4 gload16/thread @512 thr)
  auto stage = [&](int bu, int t) {
    const int kb = t * KVBLK;
#pragma unroll
    for (int j = 0; j < 2; j++) {
      int o_ = (tid + 512 * j) * 16;                 // byte offset in K tile
      int row = o_ >> 8, cb = o_ & 255;              // row stride 256B
      int scb = cb ^ ((row & 7) << 4);
      gload_lds16(kbase + (size_t)(kb + row) * HD_ + (scb >> 1),
                  &Ks[bu][0] + (o_ >> 1));
    }
#pragma unroll
    for (int j = 0; j < 2; j++) {
      int o_ = (tid + 512 * j) * 16;                 // byte offset in V tile
      int row = o_ >> 7, cb = o_ & 127;              // row stride 128B
      int scb = cb ^ ((row & 7) << 4);
      gload_lds16(vbase + (size_t)row * S_ + kb + (scb >> 1),
                  &Vs[bu][0] + (o_ >> 1));
    }
  };

  const int nt = S_ / KVBLK;
  stage(0, 0);
  __syncthreads();
  int buf = 0;

  for (int t = 0; t < nt; t++) {
    if (t + 1 < nt) stage(buf ^ 1, t + 1);
    const bf16_t* Kb = &Ks[buf][0];
    const bf16_t* Vb = &Vs[buf][0];

    // QK^T swapped: sc[m][n][i] = S[k=n*16+4lg+i][q=m*16+lr] (log2 domain)
    f32x4 sc[2][4];
#pragma unroll
    for (int m = 0; m < 2; m++)
#pragma unroll
      for (int n = 0; n < 4; n++) sc[m][n] = f32x4{0.f, 0.f, 0.f, 0.f};
    __builtin_amdgcn_s_setprio(1);
#pragma unroll
    for (int n = 0; n < 4; n++) {
#pragma unroll
      for (int kk = 0; kk < 4; kk++) {
        int r = n * 16 + lr;
        int cb = (kk * 64 + lg * 16) ^ ((r & 7) << 4);
        bf16x8 kf = *(const bf16x8*)(Kb + (((r << 8) + cb) >> 1));
        sc[0][n] = MFMA(kf, qf[0][kk], sc[0][n]);
        sc[1][n] = MFMA(kf, qf[1][kk], sc[1][n]);
      }
    }
    __builtin_amdgcn_s_setprio(0);

    // in-register softmax per m-frag
    bf16x8 pf[2][2];
#pragma unroll
    for (int m = 0; m < 2; m++) {
      // lane-local max over this lane's 16 scores (all same q-row)
      float lm = sc[m][0][0];
#pragma unroll
      for (int n = 0; n < 4; n++)
#pragma unroll
        for (int i = 0; i < 4; i++)
          if (n | i) lm = fmaxf(lm, sc[m][n][i]);
      if (!__all(lm - mR[m] <= SM_THR)) {   // trigger: tile 0 + rare growth
        float tmx = fmaxf(lm, __shfl_xor(lm, 16));
        tmx = fmaxf(tmx, __shfl_xor(tmx, 32));
        float mnew = fmaxf(mR[m], tmx);
        float alpha = exp2_fast(mR[m] - mnew);
        mR[m] = mnew;
        float av[4];
#pragma unroll
        for (int i = 0; i < 4; i++) av[i] = __shfl(alpha, lg * 4 + i);
#pragma unroll
        for (int n = 0; n < 9; n++)
#pragma unroll
          for (int i = 0; i < 4; i++) o[m][n][i] *= av[i];
      }
      // P = 2^(sc - mR), packed to bf16 words in-register
      unsigned W[4][2];
#pragma unroll
      for (int n = 0; n < 4; n++) {
        float p0 = exp2_fast(sc[m][n][0] - mR[m]);
        float p1 = exp2_fast(sc[m][n][1] - mR[m]);
        float p2 = exp2_fast(sc[m][n][2] - mR[m]);
        float p3 = exp2_fast(sc[m][n][3] - mR[m]);
        W[n][0] = cvt_pk_bf16(p0, p1);
        W[n][1] = cvt_pk_bf16(p2, p3);
      }
      // redistribute: pf[m][kk] word t <- W[2kk+(lg>>1)][t&1]
      //               from lane lr+32*(lg&1)+16*(t>>1)
#pragma unroll
      for (int kk = 0; kk < 2; kk++) {
        uint32x4 wv;
#pragma unroll
        for (int t2 = 0; t2 < 4; t2++) {
          int srcb = (t2 < 2) ? sl0 : sl1;
          unsigned lo = (unsigned)__builtin_amdgcn_ds_bpermute(srcb, (int)W[2 * kk][t2 & 1]);
          unsigned hi = (unsigned)__builtin_amdgcn_ds_bpermute(srcb, (int)W[2 * kk + 1][t2 & 1]);
          wv[t2] = (l & 32) ? hi : lo;
        }
        pf[m][kk] = __builtin_bit_cast(bf16x8, wv);
      }
    }

    // PV + row-sum: V frag loaded once, shared across both m; ones-col = lR
    __builtin_amdgcn_s_setprio(1);
#pragma unroll
    for (int n = 0; n < 8; n++) {
#pragma unroll
      for (int kk = 0; kk < 2; kk++) {
        int r = n * 16 + lr;
        int cb = (kk * 64 + lg * 16) ^ ((r & 7) << 4);
        bf16x8 vf = *(const bf16x8*)(Vb + (((r << 7) + cb) >> 1));
        o[0][n] = MFMA(pf[0][kk], vf, o[0][n]);
        o[1][n] = MFMA(pf[1][kk], vf, o[1][n]);
      }
    }
    o[0][8] = MFMA(pf[0][0], ones, o[0][8]);
    o[0][8] = MFMA(pf[0][1], ones, o[0][8]);
    o[1][8] = MFMA(pf[1][0], ones, o[1][8]);
    o[1][8] = MFMA(pf[1][1], ones, o[1][8]);
    __builtin_amdgcn_s_setprio(0);
    __syncthreads();
    buf ^= 1;
  }

#pragma unroll
  for (int m = 0; m < 2; m++)
#pragma unroll
    for (int i = 0; i < 4; i++) {
      float inv = 1.0f / o[m][8][i];
      int srow = qb * 256 + w * 32 + m * 16 + lg * 4 + i;
#pragma unroll
      for (int n = 0; n < 8; n++) {
        int d = n * 16 + lr;
        ctx[((size_t)(b * S_ + srow)) * D_ + h * HD_ + d] = (bf16_t)(o[m][n][i] * inv);
      }
    }
}

// ---------------- launch ----------------
extern "C" void kernel_launch(void* const* d_in, const int* in_sizes, int n_in,
                              void* d_out, int out_size, void* d_ws, size_t ws_size,
                              hipStream_t stream) {
  const float* x    = (const float*)d_in[0];
  const float* wq   = (const float*)d_in[1];
  const float* wk   = (const float*)d_in[2];
  const float* wv   = (const float*)d_in[3];
  const float* wo   = (const float*)d_in[4];
  const float* fcos = (const float*)d_in[5];
  const float* fsin = (const float*)d_in[6];
  float* out = (float*)d_out;

  // workspace layout (aliased; 160 MB total)
  const size_t SZ_XB    = (size_t)BS_ * D_ * 2;      // 32 MB  (xb, later qrope)
  const size_t SZ_WQKVT = (size_t)NQK_ * D_ * 2;     // 48 MB  (wqkvt, later krope+vtr)
  const size_t SZ_WOT   = (size_t)D_ * D_ * 2;       // 32 MB
  char* p = (char*)d_ws;
  bf16_t* xb    = (bf16_t*)p;                        // then qrope
  bf16_t* wqkvt = (bf16_t*)(p + SZ_XB);              // then krope, vtr
  bf16_t* wot   = (bf16_t*)(p + SZ_XB + SZ_WQKVT);
  bf16_t* qkv   = (bf16_t*)(p + SZ_XB + SZ_WQKVT + SZ_WOT);  // then ctx
  bf16_t* qrope = xb;
  bf16_t* krope = wqkvt;
  bf16_t* vtr   = wqkvt + (size_t)BS_ * NKV_ * HD_;
  bf16_t* ctx   = qkv;

  // Q pre-scale: log2(e) / sqrt(HD)  (scores land in log2 domain)
  const float QSCALE = (float)(0.08838834764831845 * 1.4426950408889634);

  dim3 tb(32, 8);
  // 1. x -> bf16
  k_cvt<<<BS_ * D_ / 1024, 256, 0, stream>>>((const float4*)x, (bf16x4*)xb, BS_ * D_ / 4);
  // 2. transpose+convert weights (fused qkv weight, then wo)
  k_transpose_cvt<<<dim3(D_ / 32, D_ / 32), tb, 0, stream>>>(wq, wqkvt, D_, D_);
  k_transpose_cvt<<<dim3(32, D_ / 32), tb, 0, stream>>>(wk, wqkvt + (size_t)D_ * D_, D_, NKV_ * HD_);
  k_transpose_cvt<<<dim3(32, D_ / 32), tb, 0, stream>>>(wv, wqkvt + (size_t)(D_ + NKV_ * HD_) * D_, D_, NKV_ * HD_);
  k_transpose_cvt<<<dim3(D_ / 32, D_ / 32), tb, 0, stream>>>(wo, wot, D_, D_);
  // 3. fused QKV projection: NF=3 single launch (512 blocks = 2 clean rounds)
  k_gemm8p<bf16_t, 3><<<dim3(BS_ / 256, NQK_ / 192), 512, 0, stream>>>(xb, wqkvt, qkv, BS_, NQK_, D_);
  // 4. RoPE + reorder (Q pre-scaled into log2 domain), V transpose
  k_rope<<<BS_ * NH_ * 64 / 256, 256, 0, stream>>>(qkv, fcos, fsin, qrope, NH_, 0, QSCALE);
  k_rope<<<BS_ * NKV_ * 64 / 256, 256, 0, stream>>>(qkv, fcos, fsin, krope, NKV_, D_, 1.0f);
  k_vtrans<<<dim3(S_ / 32, HD_ / 32, B_ * NKV_), tb, 0, stream>>>(qkv, vtr);
  // 5. flash attention: 512-thread blocks, grid (8,32,2) = 512 = 2 blocks/CU
  k_flash<<<dim3(S_ / 256, NH_, B_), 512, 0, stream>>>(qrope, krope, vtr, ctx);
  // 6. output projection -> f32 out: 256x256 tiles, grid 16x16 = 256 = 1 round
  k_gemm8p<float, 4><<<dim3(BS_ / 256, D_ / 256), 512, 0, stream>>>(ctx, wot, out, BS_, D_, D_);
}

// Round 12
// 619.059 us; speedup vs baseline: 1.5428x; 1.5428x over previous
//
#include <hip/hip_runtime.h>
#include <hip/hip_bf16.h>
#include <cstdint>

#define B_   2
#define S_   2048
#define D_   4096
#define NH_  32
#define NKV_ 8
#define HD_  128
#define BS_  (B_*S_)      // 4096 rows
#define NQK_ 6144         // NH*HD + 2*NKV*HD

typedef __bf16 bf16_t;
typedef __bf16 bf16x8 __attribute__((ext_vector_type(8)));
typedef __bf16 bf16x4 __attribute__((ext_vector_type(4)));
typedef __bf16 bf16x2 __attribute__((ext_vector_type(2)));
typedef float  f32x4  __attribute__((ext_vector_type(4)));
typedef unsigned uint32x4 __attribute__((ext_vector_type(4)));

typedef const __attribute__((address_space(1))) void* gas_ptr;
typedef __attribute__((address_space(3))) void* las_ptr;

__device__ __forceinline__ void gload_lds16(const void* g, void* l) {
  __builtin_amdgcn_global_load_lds((gas_ptr)g, (las_ptr)l, 16, 0, 0);
}

__device__ __forceinline__ float exp2_fast(float x) {   // v_exp_f32 = 2^x
  float r;
  asm("v_exp_f32 %0, %1" : "=v"(r) : "v"(x));
  return r;
}

__device__ __forceinline__ unsigned cvt_pk_bf16(float a, float b) {
  unsigned r;
  asm("v_cvt_pk_bf16_f32 %0, %1, %2" : "=v"(r) : "v"(a), "v"(b));
  return r;
}

#define LD8(p) (*(const bf16x8*)(p))
#define MFMA(a, b, c) __builtin_amdgcn_mfma_f32_16x16x32_bf16(a, b, c, 0, 0, 0)

// ---------------- f32 -> bf16 convert (vectorized) ----------------
__global__ __launch_bounds__(256) void k_cvt(const float4* __restrict__ in,
                                             bf16x4* __restrict__ out, int n4) {
  int i = blockIdx.x * 256 + threadIdx.x;
  if (i >= n4) return;
  float4 v = in[i];
  bf16x4 o = { (bf16_t)v.x, (bf16_t)v.y, (bf16_t)v.z, (bf16_t)v.w };
  out[i] = o;
}

// ---------------- w[K][N] f32 -> wt[N][K] bf16 (tiled transpose) ----------------
__global__ __launch_bounds__(256) void k_transpose_cvt(const float* __restrict__ w,
                                                       bf16_t* __restrict__ wt,
                                                       int K, int N) {
  __shared__ float tile[32][33];
  int n0 = blockIdx.x * 32, k0 = blockIdx.y * 32;
  int tx = threadIdx.x, ty = threadIdx.y;   // 32x8
#pragma unroll
  for (int i = 0; i < 4; i++)
    tile[ty + 8*i][tx] = w[(size_t)(k0 + ty + 8*i) * N + n0 + tx];
  __syncthreads();
#pragma unroll
  for (int i = 0; i < 4; i++)
    wt[(size_t)(n0 + ty + 8*i) * K + k0 + tx] = (bf16_t)tile[tx][ty + 8*i];
}

// ---------------- 256x(64*NF) NT GEMM — 4-phase/K-tile template ----------------
// NF=3 for QKV (512 blocks = 2 clean rounds), NF=4 for out-proj (256 = 1 round).
template <typename CT, int NF>
__global__ __launch_bounds__(512, 2) void k_gemm8p(const bf16_t* __restrict__ A,
                                                   const bf16_t* __restrict__ Bt,
                                                   CT* __restrict__ C,
                                                   int M, int N, int K) {
  __shared__ __align__(16) bf16_t As[2][256 * 64];       // 2 x 32 KB
  __shared__ __align__(16) bf16_t Bs[2][NF * 64 * 64];   // 2 x 8NF KB
  const int tid = threadIdx.x;
  const int l = tid & 63, w = tid >> 6;
  const int lr = l & 15, lg = l >> 4;
  const int wm = w >> 2, wn = w & 3;       // 2M x 4N wave grid

  const int bm = blockIdx.x, bn = blockIdx.y;

  const bf16_t* Ab = A  + (size_t)bm * 256 * K;
  const bf16_t* Bb = Bt + (size_t)bn * (NF * 64) * K;

  int st_row[4], st_col[4], st_dst[4];
#pragma unroll
  for (int j = 0; j < 4; j++) {
    int o = (j * 512 + tid) * 16;          // byte offset
    int row = o >> 7, cb = o & 127;        // 128B rows
    st_row[j] = row;
    st_col[j] = (cb ^ ((row & 7) << 4)) >> 1;
    st_dst[j] = o >> 1;
  }

  int aoff[8], boff[NF];
#pragma unroll
  for (int m = 0; m < 8; m++) {
    int r = wm * 128 + m * 16 + lr;
    aoff[m] = r * 64 + (((lg * 16) ^ ((r & 7) << 4)) >> 1);
  }
#pragma unroll
  for (int n = 0; n < NF; n++) {
    int r = wn * (16 * NF) + n * 16 + lr;
    boff[n] = r * 64 + (((lg * 16) ^ ((r & 7) << 4)) >> 1);
  }

  f32x4 acc[8][NF];
#pragma unroll
  for (int m = 0; m < 8; m++)
#pragma unroll
    for (int n = 0; n < NF; n++) acc[m][n] = f32x4{0.f, 0.f, 0.f, 0.f};

  auto stageA = [&](int k, int h) {       // half h: 128 rows, 2 loads
    const int kt = k << 6;
    const int rof = h << 7;
#pragma unroll
    for (int j = 0; j < 2; j++)
      gload_lds16(Ab + (size_t)(st_row[j] + rof) * K + kt + st_col[j],
                  &As[k & 1][0] + (rof << 6) + st_dst[j]);
  };
  auto stageB = [&](int k) {              // full B tile: 64NF rows, NF loads
    const int kt = k << 6;
#pragma unroll
    for (int j = 0; j < NF; j++)
      gload_lds16(Bb + (size_t)st_row[j] * K + kt + st_col[j],
                  &Bs[k & 1][0] + st_dst[j]);
  };

  const int NT = K >> 6;
  stageA(0, 0); stageA(0, 1); stageB(0); stageB(1);
  if constexpr (NF == 3) asm volatile("s_waitcnt vmcnt(3)" ::: "memory");
  else                   asm volatile("s_waitcnt vmcnt(4)" ::: "memory");
  __builtin_amdgcn_s_barrier();

  for (int k = 0; k < NT; ++k) {
    const bf16_t* Ap = &As[k & 1][0];
    const bf16_t* Bp = &Bs[k & 1][0];
    const bool s1 = (k + 1 < NT), s2 = (k + 2 < NT);
    bf16x8 bfr[NF], a[4];

    // ---- P0: b kk0 + a[0..3] kk0 ; stage A-half0(k+1) ----
#pragma unroll
    for (int n = 0; n < NF; n++) bfr[n] = LD8(Bp + boff[n]);
#pragma unroll
    for (int m = 0; m < 4; m++) a[m] = LD8(Ap + aoff[m]);
    if (s1) stageA(k + 1, 0);
    __builtin_amdgcn_s_barrier();
    asm volatile("s_waitcnt lgkmcnt(0)" ::: "memory");
    __builtin_amdgcn_s_setprio(1);
#pragma unroll
    for (int m = 0; m < 4; m++)
#pragma unroll
      for (int n = 0; n < NF; n++)
        acc[m][n] = MFMA(a[m], bfr[n], acc[m][n]);
    __builtin_amdgcn_s_setprio(0);
    __builtin_amdgcn_s_barrier();

    // ---- P1: a[4..7] kk0 ; stage A-half1(k+1) ----
#pragma unroll
    for (int m = 0; m < 4; m++) a[m] = LD8(Ap + aoff[m + 4]);
    if (s1) stageA(k + 1, 1);
    __builtin_amdgcn_s_barrier();
    asm volatile("s_waitcnt lgkmcnt(0)" ::: "memory");
    __builtin_amdgcn_s_setprio(1);
#pragma unroll
    for (int m = 0; m < 4; m++)
#pragma unroll
      for (int n = 0; n < NF; n++)
        acc[m + 4][n] = MFMA(a[m], bfr[n], acc[m + 4][n]);
    __builtin_amdgcn_s_setprio(0);
    __builtin_amdgcn_s_barrier();

    // ---- P2: b kk1 + a[0..3] kk1 ----
#pragma unroll
    for (int n = 0; n < NF; n++) bfr[n] = LD8(Bp + (boff[n] ^ 32));
#pragma unroll
    for (int m = 0; m < 4; m++) a[m] = LD8(Ap + (aoff[m] ^ 32));
    __builtin_amdgcn_s_barrier();
    asm volatile("s_waitcnt lgkmcnt(0)" ::: "memory");
    __builtin_amdgcn_s_setprio(1);
#pragma unroll
    for (int m = 0; m < 4; m++)
#pragma unroll
      for (int n = 0; n < NF; n++)
        acc[m][n] = MFMA(a[m], bfr[n], acc[m][n]);
    __builtin_amdgcn_s_setprio(0);
    __builtin_amdgcn_s_barrier();

    // ---- P3: a[4..7] kk1 ; stage B(k+2) ; boundary vmcnt ----
#pragma unroll
    for (int m = 0; m < 4; m++) a[m] = LD8(Ap + (aoff[m + 4] ^ 32));
    if (s2) {
      stageB(k + 2);
      if constexpr (NF == 3) asm volatile("s_waitcnt vmcnt(3)" ::: "memory");
      else                   asm volatile("s_waitcnt vmcnt(4)" ::: "memory");
    } else if (s1) {
      asm volatile("s_waitcnt vmcnt(0)" ::: "memory");
    }
    __builtin_amdgcn_s_barrier();
    asm volatile("s_waitcnt lgkmcnt(0)" ::: "memory");
    __builtin_amdgcn_s_setprio(1);
#pragma unroll
    for (int m = 0; m < 4; m++)
#pragma unroll
      for (int n = 0; n < NF; n++)
        acc[m + 4][n] = MFMA(a[m], bfr[n], acc[m + 4][n]);
    __builtin_amdgcn_s_setprio(0);
    __builtin_amdgcn_s_barrier();
  }

#pragma unroll
  for (int m = 0; m < 8; m++) {
    int row0 = bm * 256 + wm * 128 + m * 16 + lg * 4;
#pragma unroll
    for (int n = 0; n < NF; n++) {
      int col = bn * (NF * 64) + wn * (16 * NF) + n * 16 + lr;
#pragma unroll
      for (int i = 0; i < 4; i++)
        C[(size_t)(row0 + i) * N + col] = (CT)acc[m][n][i];
    }
  }
}

// ---------------- RoPE + head-major reorder ----------------
__global__ __launch_bounds__(256) void k_rope(const bf16_t* __restrict__ qkv,
                                              const float* __restrict__ fcos,
                                              const float* __restrict__ fsin,
                                              bf16_t* __restrict__ dst,
                                              int nheads, int col_off, float mul) {
  int idx = blockIdx.x * 256 + threadIdx.x;   // B*S*nheads*64 threads
  int p = idx & 63;
  int h = (idx >> 6) % nheads;
  int bs = idx / (64 * nheads);
  int s = bs & (S_ - 1);
  int b = bs >> 11;                            // bs / S_
  const bf16_t* src = qkv + (size_t)bs * NQK_ + col_off + h * HD_ + 2 * p;
  bf16x2 ab = *(const bf16x2*)src;
  float a = (float)ab[0], bb = (float)ab[1];
  float c = fcos[s * 64 + p], sn = fsin[s * 64 + p];
  bf16x2 o = { (bf16_t)((a * c - bb * sn) * mul), (bf16_t)((a * sn + bb * c) * mul) };
  *(bf16x2*)(dst + ((((size_t)b * nheads + h) * S_ + s) * HD_) + 2 * p) = o;
}

// ---------------- V transpose: qkv v-cols -> vt[B][NKV][HD][S] ----------------
__global__ __launch_bounds__(256) void k_vtrans(const bf16_t* __restrict__ qkv,
                                                bf16_t* __restrict__ vtr) {
  __shared__ bf16_t tile[32][33];
  int s0 = blockIdx.x * 32, d0 = blockIdx.y * 32, z = blockIdx.z;  // z = b*NKV+kvh
  int b = z >> 3, kvh = z & 7;
  int tx = threadIdx.x, ty = threadIdx.y;
#pragma unroll
  for (int i = 0; i < 4; i++)
    tile[ty + 8*i][tx] =
        qkv[(size_t)(b * S_ + s0 + ty + 8*i) * NQK_ + (D_ + NKV_ * HD_) + kvh * HD_ + d0 + tx];
  __syncthreads();
#pragma unroll
  for (int i = 0; i < 4; i++)
    vtr[((size_t)z * HD_ + d0 + ty + 8*i) * S_ + s0 + tx] = tile[tx][ty + 8*i];
}

// ---------------- Flash attention (non-causal, GQA) ----------------
// grid (S/256, NH, B), 512 thr (8 waves). Wave w owns q rows [qb*256+w*32, +32).
// K/V LDS (64 KB) shared by 8 waves -> target 2 blocks/CU = 16 waves/CU.
// __launch_bounds__(512, 2): round-11's (512,4) made hipcc cap VGPR at 64
// (computed 32 waves/CU) -> 40-reg spill, WRITE_SIZE 866 MB, 2.6x slower.
// (512,2) caps at 128-256; kernel naturally needs ~104 (round-10 precedent)
// -> no spill, and 104<=128 VGPR + 64KB LDS lets HW run 2 blocks/CU.
#define KVBLK 64
#define SM_THR 12.0f     // log2-domain defer threshold (P bounded by 2^12)
__global__ __launch_bounds__(512, 2) void k_flash(const bf16_t* __restrict__ qr,
                                                  const bf16_t* __restrict__ kr,
                                                  const bf16_t* __restrict__ vt,
                                                  bf16_t* __restrict__ ctx) {
  __shared__ __align__(16) bf16_t Ks[2][KVBLK * HD_];   // 2 x 16 KB [row s][col d]
  __shared__ __align__(16) bf16_t Vs[2][HD_ * KVBLK];   // 2 x 16 KB [row d][col s]
  const int tid = threadIdx.x;
  const int l = tid & 63, w = tid >> 6;                 // 8 waves
  const int lr = l & 15, lg = l >> 4;
  const int qb = blockIdx.x, h = blockIdx.y, b = blockIdx.z;
  const int kvh = h >> 2;   // NREP=4

  const bf16_t* qbase = qr + (((size_t)b * NH_ + h) * S_ + qb * 256 + w * 32) * HD_;
  const bf16_t* kbase = kr + (((size_t)b * NKV_ + kvh) * S_) * HD_;
  const bf16_t* vbase = vt + (((size_t)b * NKV_ + kvh) * HD_) * S_;

  // bpermute byte addrs: src lane = lr + 32*(lg&1) (+16 for t>=2)
  const int sl0 = (lr + ((lg & 1) << 5)) << 2;
  const int sl1 = sl0 + (16 << 2);

  // Q fragments (pre-scaled by log2e/sqrt(HD) in k_rope)
  bf16x8 qf[2][4];
#pragma unroll
  for (int m = 0; m < 2; m++)
#pragma unroll
    for (int kk = 0; kk < 4; kk++)
      qf[m][kk] = *(const bf16x8*)(qbase + (m * 16 + lr) * HD_ + kk * 32 + lg * 8);

  bf16x8 ones;
#pragma unroll
  for (int j = 0; j < 8; j++) ones[j] = (bf16_t)1.0f;

  f32x4 o[2][9];                     // [..][8] = row-sum accumulator
#pragma unroll
  for (int m = 0; m < 2; m++)
#pragma unroll
    for (int n = 0; n < 9; n++) o[m][n] = f32x4{0.f, 0.f, 0.f, 0.f};
  float mR[2] = {-1e30f, -1e30f};    // per-lane scalar: lane's q = m*16+lr

  // stage tile t into buffer bu (K: 16KB, V: 16KB; 4 gload16/thread @512 thr)
  auto stage = [&](int bu, int t) {
    const int kb = t * KVBLK;
#pragma unroll
    for (int j = 0; j < 2; j++) {
      int o_ = (tid + 512 * j) * 16;                 // byte offset in K tile
      int row = o_ >> 8, cb = o_ & 255;              // row stride 256B
      int scb = cb ^ ((row & 7) << 4);
      gload_lds16(kbase + (size_t)(kb + row) * HD_ + (scb >> 1),
                  &Ks[bu][0] + (o_ >> 1));
    }
#pragma unroll
    for (int j = 0; j < 2; j++) {
      int o_ = (tid + 512 * j) * 16;                 // byte offset in V tile
      int row = o_ >> 7, cb = o_ & 127;              // row stride 128B
      int scb = cb ^ ((row & 7) << 4);
      gload_lds16(vbase + (size_t)row * S_ + kb + (scb >> 1),
                  &Vs[bu][0] + (o_ >> 1));
    }
  };

  const int nt = S_ / KVBLK;
  stage(0, 0);
  __syncthreads();
  int buf = 0;

  for (int t = 0; t < nt; t++) {
    if (t + 1 < nt) stage(buf ^ 1, t + 1);
    const bf16_t* Kb = &Ks[buf][0];
    const bf16_t* Vb = &Vs[buf][0];

    // QK^T swapped: sc[m][n][i] = S[k=n*16+4lg+i][q=m*16+lr] (log2 domain)
    f32x4 sc[2][4];
#pragma unroll
    for (int m = 0; m < 2; m++)
#pragma unroll
      for (int n = 0; n < 4; n++) sc[m][n] = f32x4{0.f, 0.f, 0.f, 0.f};
    __builtin_amdgcn_s_setprio(1);
#pragma unroll
    for (int n = 0; n < 4; n++) {
#pragma unroll
      for (int kk = 0; kk < 4; kk++) {
        int r = n * 16 + lr;
        int cb = (kk * 64 + lg * 16) ^ ((r & 7) << 4);
        bf16x8 kf = *(const bf16x8*)(Kb + (((r << 8) + cb) >> 1));
        sc[0][n] = MFMA(kf, qf[0][kk], sc[0][n]);
        sc[1][n] = MFMA(kf, qf[1][kk], sc[1][n]);
      }
    }
    __builtin_amdgcn_s_setprio(0);

    // in-register softmax per m-frag
    bf16x8 pf[2][2];
#pragma unroll
    for (int m = 0; m < 2; m++) {
      // lane-local max over this lane's 16 scores (all same q-row)
      float lm = sc[m][0][0];
#pragma unroll
      for (int n = 0; n < 4; n++)
#pragma unroll
        for (int i = 0; i < 4; i++)
          if (n | i) lm = fmaxf(lm, sc[m][n][i]);
      if (!__all(lm - mR[m] <= SM_THR)) {   // trigger: tile 0 + rare growth
        float tmx = fmaxf(lm, __shfl_xor(lm, 16));
        tmx = fmaxf(tmx, __shfl_xor(tmx, 32));
        float mnew = fmaxf(mR[m], tmx);
        float alpha = exp2_fast(mR[m] - mnew);
        mR[m] = mnew;
        float av[4];
#pragma unroll
        for (int i = 0; i < 4; i++) av[i] = __shfl(alpha, lg * 4 + i);
#pragma unroll
        for (int n = 0; n < 9; n++)
#pragma unroll
          for (int i = 0; i < 4; i++) o[m][n][i] *= av[i];
      }
      // P = 2^(sc - mR), packed to bf16 words in-register
      unsigned W[4][2];
#pragma unroll
      for (int n = 0; n < 4; n++) {
        float p0 = exp2_fast(sc[m][n][0] - mR[m]);
        float p1 = exp2_fast(sc[m][n][1] - mR[m]);
        float p2 = exp2_fast(sc[m][n][2] - mR[m]);
        float p3 = exp2_fast(sc[m][n][3] - mR[m]);
        W[n][0] = cvt_pk_bf16(p0, p1);
        W[n][1] = cvt_pk_bf16(p2, p3);
      }
      // redistribute: pf[m][kk] word t <- W[2kk+(lg>>1)][t&1]
      //               from lane lr+32*(lg&1)+16*(t>>1)
#pragma unroll
      for (int kk = 0; kk < 2; kk++) {
        uint32x4 wv;
#pragma unroll
        for (int t2 = 0; t2 < 4; t2++) {
          int srcb = (t2 < 2) ? sl0 : sl1;
          unsigned lo = (unsigned)__builtin_amdgcn_ds_bpermute(srcb, (int)W[2 * kk][t2 & 1]);
          unsigned hi = (unsigned)__builtin_amdgcn_ds_bpermute(srcb, (int)W[2 * kk + 1][t2 & 1]);
          wv[t2] = (l & 32) ? hi : lo;
        }
        pf[m][kk] = __builtin_bit_cast(bf16x8, wv);
      }
    }

    // PV + row-sum: V frag loaded once, shared across both m; ones-col = lR
    __builtin_amdgcn_s_setprio(1);
#pragma unroll
    for (int n = 0; n < 8; n++) {
#pragma unroll
      for (int kk = 0; kk < 2; kk++) {
        int r = n * 16 + lr;
        int cb = (kk * 64 + lg * 16) ^ ((r & 7) << 4);
        bf16x8 vf = *(const bf16x8*)(Vb + (((r << 7) + cb) >> 1));
        o[0][n] = MFMA(pf[0][kk], vf, o[0][n]);
        o[1][n] = MFMA(pf[1][kk], vf, o[1][n]);
      }
    }
    o[0][8] = MFMA(pf[0][0], ones, o[0][8]);
    o[0][8] = MFMA(pf[0][1], ones, o[0][8]);
    o[1][8] = MFMA(pf[1][0], ones, o[1][8]);
    o[1][8] = MFMA(pf[1][1], ones, o[1][8]);
    __builtin_amdgcn_s_setprio(0);
    __syncthreads();
    buf ^= 1;
  }

#pragma unroll
  for (int m = 0; m < 2; m++)
#pragma unroll
    for (int i = 0; i < 4; i++) {
      float inv = 1.0f / o[m][8][i];
      int srow = qb * 256 + w * 32 + m * 16 + lg * 4 + i;
#pragma unroll
      for (int n = 0; n < 8; n++) {
        int d = n * 16 + lr;
        ctx[((size_t)(b * S_ + srow)) * D_ + h * HD_ + d] = (bf16_t)(o[m][n][i] * inv);
      }
    }
}

// ---------------- launch ----------------
extern "C" void kernel_launch(void* const* d_in, const int* in_sizes, int n_in,
                              void* d_out, int out_size, void* d_ws, size_t ws_size,
                              hipStream_t stream) {
  const float* x    = (const float*)d_in[0];
  const float* wq   = (const float*)d_in[1];
  const float* wk   = (const float*)d_in[2];
  const float* wv   = (const float*)d_in[3];
  const float* wo   = (const float*)d_in[4];
  const float* fcos = (const float*)d_in[5];
  const float* fsin = (const float*)d_in[6];
  float* out = (float*)d_out;

  // workspace layout (aliased; 160 MB total)
  const size_t SZ_XB    = (size_t)BS_ * D_ * 2;      // 32 MB  (xb, later qrope)
  const size_t SZ_WQKVT = (size_t)NQK_ * D_ * 2;     // 48 MB  (wqkvt, later krope+vtr)
  const size_t SZ_WOT   = (size_t)D_ * D_ * 2;       // 32 MB
  char* p = (char*)d_ws;
  bf16_t* xb    = (bf16_t*)p;                        // then qrope
  bf16_t* wqkvt = (bf16_t*)(p + SZ_XB);              // then krope, vtr
  bf16_t* wot   = (bf16_t*)(p + SZ_XB + SZ_WQKVT);
  bf16_t* qkv   = (bf16_t*)(p + SZ_XB + SZ_WQKVT + SZ_WOT);  // then ctx
  bf16_t* qrope = xb;
  bf16_t* krope = wqkvt;
  bf16_t* vtr   = wqkvt + (size_t)BS_ * NKV_ * HD_;
  bf16_t* ctx   = qkv;

  // Q pre-scale: log2(e) / sqrt(HD)  (scores land in log2 domain)
  const float QSCALE = (float)(0.08838834764831845 * 1.4426950408889634);

  dim3 tb(32, 8);
  // 1. x -> bf16
  k_cvt<<<BS_ * D_ / 1024, 256, 0, stream>>>((const float4*)x, (bf16x4*)xb, BS_ * D_ / 4);
  // 2. transpose+convert weights (fused qkv weight, then wo)
  k_transpose_cvt<<<dim3(D_ / 32, D_ / 32), tb, 0, stream>>>(wq, wqkvt, D_, D_);
  k_transpose_cvt<<<dim3(32, D_ / 32), tb, 0, stream>>>(wk, wqkvt + (size_t)D_ * D_, D_, NKV_ * HD_);
  k_transpose_cvt<<<dim3(32, D_ / 32), tb, 0, stream>>>(wv, wqkvt + (size_t)(D_ + NKV_ * HD_) * D_, D_, NKV_ * HD_);
  k_transpose_cvt<<<dim3(D_ / 32, D_ / 32), tb, 0, stream>>>(wo, wot, D_, D_);
  // 3. fused QKV projection: NF=3 single launch (512 blocks = 2 clean rounds)
  k_gemm8p<bf16_t, 3><<<dim3(BS_ / 256, NQK_ / 192), 512, 0, stream>>>(xb, wqkvt, qkv, BS_, NQK_, D_);
  // 4. RoPE + reorder (Q pre-scaled into log2 domain), V transpose
  k_rope<<<BS_ * NH_ * 64 / 256, 256, 0, stream>>>(qkv, fcos, fsin, qrope, NH_, 0, QSCALE);
  k_rope<<<BS_ * NKV_ * 64 / 256, 256, 0, stream>>>(qkv, fcos, fsin, krope, NKV_, D_, 1.0f);
  k_vtrans<<<dim3(S_ / 32, HD_ / 32, B_ * NKV_), tb, 0, stream>>>(qkv, vtr);
  // 5. flash attention: 512-thread blocks, grid (8,32,2) = 512 = 2 blocks/CU
  k_flash<<<dim3(S_ / 256, NH_, B_), 512, 0, stream>>>(qrope, krope, vtr, ctx);
  // 6. output projection -> f32 out: 256x256 tiles, grid 16x16 = 256 = 1 round
  k_gemm8p<float, 4><<<dim3(BS_ / 256, D_ / 256), 512, 0, stream>>>(ctx, wot, out, BS_, D_, D_);
}

// Round 13
// 575.122 us; speedup vs baseline: 1.6606x; 1.0764x over previous
//
#include <hip/hip_runtime.h>
#include <hip/hip_bf16.h>
#include <cstdint>

#define B_   2
#define S_   2048
#define D_   4096
#define NH_  32
#define NKV_ 8
#define HD_  128
#define BS_  (B_*S_)      // 4096 rows
#define NQK_ 6144

typedef __bf16 bf16_t;
typedef __bf16 bf16x8 __attribute__((ext_vector_type(8)));
typedef __bf16 bf16x4 __attribute__((ext_vector_type(4)));
typedef __bf16 bf16x2 __attribute__((ext_vector_type(2)));
typedef float  f32x4  __attribute__((ext_vector_type(4)));
typedef unsigned uint32x4 __attribute__((ext_vector_type(4)));

typedef const __attribute__((address_space(1))) void* gas_ptr;
typedef __attribute__((address_space(3))) void* las_ptr;

__device__ __forceinline__ void gload_lds16(const void* g, void* l) {
  __builtin_amdgcn_global_load_lds((gas_ptr)g, (las_ptr)l, 16, 0, 0);
}

__device__ __forceinline__ float exp2_fast(float x) {   // v_exp_f32 = 2^x
  float r;
  asm("v_exp_f32 %0, %1" : "=v"(r) : "v"(x));
  return r;
}

__device__ __forceinline__ unsigned cvt_pk_bf16(float a, float b) {
  unsigned r;
  asm("v_cvt_pk_bf16_f32 %0, %1, %2" : "=v"(r) : "v"(a), "v"(b));
  return r;
}

#define LD8(p) (*(const bf16x8*)(p))
#define MFMA(a, b, c) __builtin_amdgcn_mfma_f32_16x16x32_bf16(a, b, c, 0, 0, 0)

// ---------------- f32 -> bf16 convert (vectorized) ----------------
__global__ __launch_bounds__(256) void k_cvt(const float4* __restrict__ in,
                                             bf16x4* __restrict__ out, int n4) {
  int i = blockIdx.x * 256 + threadIdx.x;
  if (i >= n4) return;
  float4 v = in[i];
  bf16x4 o = { (bf16_t)v.x, (bf16_t)v.y, (bf16_t)v.z, (bf16_t)v.w };
  out[i] = o;
}

// ---------------- w[K][N] f32 -> wt[N][K] bf16 (tiled transpose) ----------------
__global__ __launch_bounds__(256) void k_transpose_cvt(const float* __restrict__ w,
                                                       bf16_t* __restrict__ wt,
                                                       int K, int N) {
  __shared__ float tile[32][33];
  int n0 = blockIdx.x * 32, k0 = blockIdx.y * 32;
  int tx = threadIdx.x, ty = threadIdx.y;   // 32x8
#pragma unroll
  for (int i = 0; i < 4; i++)
    tile[ty + 8*i][tx] = w[(size_t)(k0 + ty + 8*i) * N + n0 + tx];
  __syncthreads();
#pragma unroll
  for (int i = 0; i < 4; i++)
    wt[(size_t)(n0 + ty + 8*i) * K + k0 + tx] = (bf16_t)tile[tx][ty + 8*i];
}

// ---------------- 256x256 NT GEMM — 4-phase/K-tile template (NF=4) ------------
// C tile at (bm*256, bn*256), stride N. KL = K-loop length; blockIdx.z selects
// a K-slice (kOff = z*KL) and a C part buffer (C += z*zsC, signed) — split-K:
// parts are summed downstream. A/Bt row stride is K (full).
template <typename CT>
__global__ __launch_bounds__(512, 2) void k_gemm8p(const bf16_t* __restrict__ A,
                                                   const bf16_t* __restrict__ Bt,
                                                   CT* __restrict__ C,
                                                   int M, int N, int K, int KL,
                                                   long long zsC) {
  constexpr int NF = 4;
  __shared__ __align__(16) bf16_t As[2][256 * 64];       // 2 x 32 KB
  __shared__ __align__(16) bf16_t Bs[2][NF * 64 * 64];   // 2 x 32 KB
  const int tid = threadIdx.x;
  const int l = tid & 63, w = tid >> 6;
  const int lr = l & 15, lg = l >> 4;
  const int wm = w >> 2, wn = w & 3;       // 2M x 4N wave grid

  const int bm = blockIdx.x, bn = blockIdx.y;
  const int kOff = blockIdx.z * KL;

  const bf16_t* Ab = A  + (size_t)bm * 256 * K + kOff;
  const bf16_t* Bb = Bt + (size_t)bn * 256 * K + kOff;
  C += (long long)blockIdx.z * zsC;

  int st_row[4], st_col[4], st_dst[4];
#pragma unroll
  for (int j = 0; j < 4; j++) {
    int o = (j * 512 + tid) * 16;          // byte offset
    int row = o >> 7, cb = o & 127;        // 128B rows
    st_row[j] = row;
    st_col[j] = (cb ^ ((row & 7) << 4)) >> 1;
    st_dst[j] = o >> 1;
  }

  int aoff[8], boff[NF];
#pragma unroll
  for (int m = 0; m < 8; m++) {
    int r = wm * 128 + m * 16 + lr;
    aoff[m] = r * 64 + (((lg * 16) ^ ((r & 7) << 4)) >> 1);
  }
#pragma unroll
  for (int n = 0; n < NF; n++) {
    int r = wn * 64 + n * 16 + lr;
    boff[n] = r * 64 + (((lg * 16) ^ ((r & 7) << 4)) >> 1);
  }

  f32x4 acc[8][NF];
#pragma unroll
  for (int m = 0; m < 8; m++)
#pragma unroll
    for (int n = 0; n < NF; n++) acc[m][n] = f32x4{0.f, 0.f, 0.f, 0.f};

  auto stageA = [&](int k, int h) {       // half h: 128 rows, 2 loads
    const int kt = k << 6;
    const int rof = h << 7;
#pragma unroll
    for (int j = 0; j < 2; j++)
      gload_lds16(Ab + (size_t)(st_row[j] + rof) * K + kt + st_col[j],
                  &As[k & 1][0] + (rof << 6) + st_dst[j]);
  };
  auto stageB = [&](int k) {              // full B tile: 256 rows, 4 loads
    const int kt = k << 6;
#pragma unroll
    for (int j = 0; j < NF; j++)
      gload_lds16(Bb + (size_t)st_row[j] * K + kt + st_col[j],
                  &Bs[k & 1][0] + st_dst[j]);
  };

  const int NT = KL >> 6;
  stageA(0, 0); stageA(0, 1); stageB(0); stageB(1);
  asm volatile("s_waitcnt vmcnt(4)" ::: "memory");
  __builtin_amdgcn_s_barrier();

  for (int k = 0; k < NT; ++k) {
    const bf16_t* Ap = &As[k & 1][0];
    const bf16_t* Bp = &Bs[k & 1][0];
    const bool s1 = (k + 1 < NT), s2 = (k + 2 < NT);
    bf16x8 bfr[NF], a[4];

    // ---- P0: b kk0 + a[0..3] kk0 ; stage A-half0(k+1) ----
#pragma unroll
    for (int n = 0; n < NF; n++) bfr[n] = LD8(Bp + boff[n]);
#pragma unroll
    for (int m = 0; m < 4; m++) a[m] = LD8(Ap + aoff[m]);
    if (s1) stageA(k + 1, 0);
    __builtin_amdgcn_s_barrier();
    asm volatile("s_waitcnt lgkmcnt(0)" ::: "memory");
    __builtin_amdgcn_s_setprio(1);
#pragma unroll
    for (int m = 0; m < 4; m++)
#pragma unroll
      for (int n = 0; n < NF; n++)
        acc[m][n] = MFMA(a[m], bfr[n], acc[m][n]);
    __builtin_amdgcn_s_setprio(0);
    __builtin_amdgcn_s_barrier();

    // ---- P1: a[4..7] kk0 ; stage A-half1(k+1) ----
#pragma unroll
    for (int m = 0; m < 4; m++) a[m] = LD8(Ap + aoff[m + 4]);
    if (s1) stageA(k + 1, 1);
    __builtin_amdgcn_s_barrier();
    asm volatile("s_waitcnt lgkmcnt(0)" ::: "memory");
    __builtin_amdgcn_s_setprio(1);
#pragma unroll
    for (int m = 0; m < 4; m++)
#pragma unroll
      for (int n = 0; n < NF; n++)
        acc[m + 4][n] = MFMA(a[m], bfr[n], acc[m + 4][n]);
    __builtin_amdgcn_s_setprio(0);
    __builtin_amdgcn_s_barrier();

    // ---- P2: b kk1 + a[0..3] kk1 ----
#pragma unroll
    for (int n = 0; n < NF; n++) bfr[n] = LD8(Bp + (boff[n] ^ 32));
#pragma unroll
    for (int m = 0; m < 4; m++) a[m] = LD8(Ap + (aoff[m] ^ 32));
    __builtin_amdgcn_s_barrier();
    asm volatile("s_waitcnt lgkmcnt(0)" ::: "memory");
    __builtin_amdgcn_s_setprio(1);
#pragma unroll
    for (int m = 0; m < 4; m++)
#pragma unroll
      for (int n = 0; n < NF; n++)
        acc[m][n] = MFMA(a[m], bfr[n], acc[m][n]);
    __builtin_amdgcn_s_setprio(0);
    __builtin_amdgcn_s_barrier();

    // ---- P3: a[4..7] kk1 ; stage B(k+2) ; boundary vmcnt ----
#pragma unroll
    for (int m = 0; m < 4; m++) a[m] = LD8(Ap + (aoff[m + 4] ^ 32));
    if (s2) {
      stageB(k + 2);
      asm volatile("s_waitcnt vmcnt(4)" ::: "memory");
    } else if (s1) {
      asm volatile("s_waitcnt vmcnt(0)" ::: "memory");
    }
    __builtin_amdgcn_s_barrier();
    asm volatile("s_waitcnt lgkmcnt(0)" ::: "memory");
    __builtin_amdgcn_s_setprio(1);
#pragma unroll
    for (int m = 0; m < 4; m++)
#pragma unroll
      for (int n = 0; n < NF; n++)
        acc[m + 4][n] = MFMA(a[m], bfr[n], acc[m + 4][n]);
    __builtin_amdgcn_s_setprio(0);
    __builtin_amdgcn_s_barrier();
  }

#pragma unroll
  for (int m = 0; m < 8; m++) {
    int row0 = bm * 256 + wm * 128 + m * 16 + lg * 4;
#pragma unroll
    for (int n = 0; n < NF; n++) {
      int col = bn * 256 + wn * 64 + n * 16 + lr;
#pragma unroll
      for (int i = 0; i < 4; i++)
        C[(size_t)(row0 + i) * N + col] = (CT)acc[m][n][i];
    }
  }
}

// ---------------- RoPE + head-major reorder (optionally sums two parts) -------
__global__ __launch_bounds__(256) void k_rope(const bf16_t* __restrict__ s1,
                                              const bf16_t* __restrict__ s2,
                                              const float* __restrict__ fcos,
                                              const float* __restrict__ fsin,
                                              bf16_t* __restrict__ dst,
                                              int nheads, int stride, float mul) {
  int idx = blockIdx.x * 256 + threadIdx.x;
  int p = idx & 63;
  int h = (idx >> 6) % nheads;
  int bs = idx / (64 * nheads);
  int s = bs & (S_ - 1);
  int b = bs >> 11;
  size_t off = (size_t)bs * stride + h * HD_ + 2 * p;
  bf16x2 ab = *(const bf16x2*)(s1 + off);
  float a = (float)ab[0], bb = (float)ab[1];
  if (s2) {
    bf16x2 ab2 = *(const bf16x2*)(s2 + off);
    a += (float)ab2[0]; bb += (float)ab2[1];
  }
  float c = fcos[s * 64 + p], sn = fsin[s * 64 + p];
  bf16x2 o = { (bf16_t)((a * c - bb * sn) * mul), (bf16_t)((a * sn + bb * c) * mul) };
  *(bf16x2*)(dst + ((((size_t)b * nheads + h) * S_ + s) * HD_) + 2 * p) = o;
}

// ---------------- V transpose from KV parts: -> vt[B][NKV][HD][S] -------------
// Parts are [BS][2048]: k heads cols 0-1023, v heads cols 1024-2047.
__global__ __launch_bounds__(256) void k_vtrans(const bf16_t* __restrict__ pA,
                                                const bf16_t* __restrict__ pB,
                                                bf16_t* __restrict__ vtr) {
  __shared__ bf16_t tile[32][33];
  int s0 = blockIdx.x * 32, d0 = blockIdx.y * 32, z = blockIdx.z;  // z = b*NKV+kvh
  int b = z >> 3, kvh = z & 7;
  int tx = threadIdx.x, ty = threadIdx.y;
#pragma unroll
  for (int i = 0; i < 4; i++) {
    size_t off = (size_t)(b * S_ + s0 + ty + 8*i) * 2048 + 1024 + kvh * HD_ + d0 + tx;
    tile[ty + 8*i][tx] = (bf16_t)((float)pA[off] + (float)pB[off]);
  }
  __syncthreads();
#pragma unroll
  for (int i = 0; i < 4; i++)
    vtr[((size_t)z * HD_ + d0 + ty + 8*i) * S_ + s0 + tx] = tile[tx][ty + 8*i];
}

// ---------------- Flash attention (round-10 version: 256 thr, 4 waves) --------
// grid (S/128, NH, B). Wave w owns q rows [qb*128+w*32, +32). Swapped QK^T
// (T12) in-register softmax, log2 domain, ones-column row-sum.
#define KVBLK 64
#define SM_THR 12.0f
__global__ __launch_bounds__(256, 2) void k_flash(const bf16_t* __restrict__ qr,
                                                  const bf16_t* __restrict__ kr,
                                                  const bf16_t* __restrict__ vt,
                                                  bf16_t* __restrict__ ctx) {
  __shared__ __align__(16) bf16_t Ks[2][KVBLK * HD_];   // 2 x 16 KB
  __shared__ __align__(16) bf16_t Vs[2][HD_ * KVBLK];   // 2 x 16 KB
  const int tid = threadIdx.x;
  const int l = tid & 63, w = tid >> 6;
  const int lr = l & 15, lg = l >> 4;
  const int qb = blockIdx.x, h = blockIdx.y, b = blockIdx.z;
  const int kvh = h >> 2;   // NREP=4

  const bf16_t* qbase = qr + (((size_t)b * NH_ + h) * S_ + qb * 128 + w * 32) * HD_;
  const bf16_t* kbase = kr + (((size_t)b * NKV_ + kvh) * S_) * HD_;
  const bf16_t* vbase = vt + (((size_t)b * NKV_ + kvh) * HD_) * S_;

  const int sl0 = (lr + ((lg & 1) << 5)) << 2;
  const int sl1 = sl0 + (16 << 2);

  bf16x8 qf[2][4];
#pragma unroll
  for (int m = 0; m < 2; m++)
#pragma unroll
    for (int kk = 0; kk < 4; kk++)
      qf[m][kk] = *(const bf16x8*)(qbase + (m * 16 + lr) * HD_ + kk * 32 + lg * 8);

  bf16x8 ones;
#pragma unroll
  for (int j = 0; j < 8; j++) ones[j] = (bf16_t)1.0f;

  f32x4 o[2][9];
#pragma unroll
  for (int m = 0; m < 2; m++)
#pragma unroll
    for (int n = 0; n < 9; n++) o[m][n] = f32x4{0.f, 0.f, 0.f, 0.f};
  float mR[2] = {-1e30f, -1e30f};

  auto stage = [&](int bu, int t) {
    const int kb = t * KVBLK;
#pragma unroll
    for (int j = 0; j < 4; j++) {
      int o_ = (tid + 256 * j) * 16;
      int row = o_ >> 8, cb = o_ & 255;
      int scb = cb ^ ((row & 7) << 4);
      gload_lds16(kbase + (size_t)(kb + row) * HD_ + (scb >> 1),
                  &Ks[bu][0] + (o_ >> 1));
    }
#pragma unroll
    for (int j = 0; j < 4; j++) {
      int o_ = (tid + 256 * j) * 16;
      int row = o_ >> 7, cb = o_ & 127;
      int scb = cb ^ ((row & 7) << 4);
      gload_lds16(vbase + (size_t)row * S_ + kb + (scb >> 1),
                  &Vs[bu][0] + (o_ >> 1));
    }
  };

  const int nt = S_ / KVBLK;
  stage(0, 0);
  __syncthreads();
  int buf = 0;

  for (int t = 0; t < nt; t++) {
    if (t + 1 < nt) stage(buf ^ 1, t + 1);
    const bf16_t* Kb = &Ks[buf][0];
    const bf16_t* Vb = &Vs[buf][0];

    f32x4 sc[2][4];
#pragma unroll
    for (int m = 0; m < 2; m++)
#pragma unroll
      for (int n = 0; n < 4; n++) sc[m][n] = f32x4{0.f, 0.f, 0.f, 0.f};
    __builtin_amdgcn_s_setprio(1);
#pragma unroll
    for (int n = 0; n < 4; n++) {
#pragma unroll
      for (int kk = 0; kk < 4; kk++) {
        int r = n * 16 + lr;
        int cb = (kk * 64 + lg * 16) ^ ((r & 7) << 4);
        bf16x8 kf = *(const bf16x8*)(Kb + (((r << 8) + cb) >> 1));
        sc[0][n] = MFMA(kf, qf[0][kk], sc[0][n]);
        sc[1][n] = MFMA(kf, qf[1][kk], sc[1][n]);
      }
    }
    __builtin_amdgcn_s_setprio(0);

    bf16x8 pf[2][2];
#pragma unroll
    for (int m = 0; m < 2; m++) {
      float lm = sc[m][0][0];
#pragma unroll
      for (int n = 0; n < 4; n++)
#pragma unroll
        for (int i = 0; i < 4; i++)
          if (n | i) lm = fmaxf(lm, sc[m][n][i]);
      if (!__all(lm - mR[m] <= SM_THR)) {
        float tmx = fmaxf(lm, __shfl_xor(lm, 16));
        tmx = fmaxf(tmx, __shfl_xor(tmx, 32));
        float mnew = fmaxf(mR[m], tmx);
        float alpha = exp2_fast(mR[m] - mnew);
        mR[m] = mnew;
        float av[4];
#pragma unroll
        for (int i = 0; i < 4; i++) av[i] = __shfl(alpha, lg * 4 + i);
#pragma unroll
        for (int n = 0; n < 9; n++)
#pragma unroll
          for (int i = 0; i < 4; i++) o[m][n][i] *= av[i];
      }
      unsigned W[4][2];
#pragma unroll
      for (int n = 0; n < 4; n++) {
        float p0 = exp2_fast(sc[m][n][0] - mR[m]);
        float p1 = exp2_fast(sc[m][n][1] - mR[m]);
        float p2 = exp2_fast(sc[m][n][2] - mR[m]);
        float p3 = exp2_fast(sc[m][n][3] - mR[m]);
        W[n][0] = cvt_pk_bf16(p0, p1);
        W[n][1] = cvt_pk_bf16(p2, p3);
      }
#pragma unroll
      for (int kk = 0; kk < 2; kk++) {
        uint32x4 wv;
#pragma unroll
        for (int t2 = 0; t2 < 4; t2++) {
          int srcb = (t2 < 2) ? sl0 : sl1;
          unsigned lo = (unsigned)__builtin_amdgcn_ds_bpermute(srcb, (int)W[2 * kk][t2 & 1]);
          unsigned hi = (unsigned)__builtin_amdgcn_ds_bpermute(srcb, (int)W[2 * kk + 1][t2 & 1]);
          wv[t2] = (l & 32) ? hi : lo;
        }
        pf[m][kk] = __builtin_bit_cast(bf16x8, wv);
      }
    }

    __builtin_amdgcn_s_setprio(1);
#pragma unroll
    for (int n = 0; n < 8; n++) {
#pragma unroll
      for (int kk = 0; kk < 2; kk++) {
        int r = n * 16 + lr;
        int cb = (kk * 64 + lg * 16) ^ ((r & 7) << 4);
        bf16x8 vf = *(const bf16x8*)(Vb + (((r << 7) + cb) >> 1));
        o[0][n] = MFMA(pf[0][kk], vf, o[0][n]);
        o[1][n] = MFMA(pf[1][kk], vf, o[1][n]);
      }
    }
    o[0][8] = MFMA(pf[0][0], ones, o[0][8]);
    o[0][8] = MFMA(pf[0][1], ones, o[0][8]);
    o[1][8] = MFMA(pf[1][0], ones, o[1][8]);
    o[1][8] = MFMA(pf[1][1], ones, o[1][8]);
    __builtin_amdgcn_s_setprio(0);
    __syncthreads();
    buf ^= 1;
  }

#pragma unroll
  for (int m = 0; m < 2; m++)
#pragma unroll
    for (int i = 0; i < 4; i++) {
      float inv = 1.0f / o[m][8][i];
      int srow = qb * 128 + w * 32 + m * 16 + lg * 4 + i;
#pragma unroll
      for (int n = 0; n < 8; n++) {
        int d = n * 16 + lr;
        ctx[((size_t)(b * S_ + srow)) * D_ + h * HD_ + d] = (bf16_t)(o[m][n][i] * inv);
      }
    }
}

// ---------------- launch ----------------
extern "C" void kernel_launch(void* const* d_in, const int* in_sizes, int n_in,
                              void* d_out, int out_size, void* d_ws, size_t ws_size,
                              hipStream_t stream) {
  const float* x    = (const float*)d_in[0];
  const float* wq   = (const float*)d_in[1];
  const float* wk   = (const float*)d_in[2];
  const float* wv   = (const float*)d_in[3];
  const float* wo   = (const float*)d_in[4];
  const float* fcos = (const float*)d_in[5];
  const float* fsin = (const float*)d_in[6];
  float* out = (float*)d_out;

  // workspace layout (160 MB, aliased):
  //  [  0, 32) xb            -> qrope after gemms
  //  [ 32, 80) wqkvt (wq 32 @32, wk/wv 16 @64) -> krope(8)+vtr(8) @[32,48)
  //  [ 80,112) wot; first 16 MB doubles as KV partB BEFORE wo transpose
  //  [112,144) qc (Q-proj out, stride D_) -> ctx after rope-Q
  //  [144,160) KV partA (stride 2048)
  const size_t MB = 1u << 20;
  char* p = (char*)d_ws;
  bf16_t* xb    = (bf16_t*)p;
  bf16_t* wqkvt = (bf16_t*)(p + 32 * MB);
  bf16_t* wot   = (bf16_t*)(p + 80 * MB);
  bf16_t* qc    = (bf16_t*)(p + 112 * MB);
  bf16_t* partA = (bf16_t*)(p + 144 * MB);
  bf16_t* partB = wot;
  bf16_t* qrope = xb;
  bf16_t* krope = wqkvt;
  bf16_t* vtr   = wqkvt + (size_t)BS_ * NKV_ * HD_;
  bf16_t* ctx   = qc;

  // Q pre-scale: log2(e) / sqrt(HD)  (scores land in log2 domain)
  const float QSCALE = (float)(0.08838834764831845 * 1.4426950408889634);

  dim3 tb(32, 8);
  // 1. x -> bf16
  k_cvt<<<BS_ * D_ / 1024, 256, 0, stream>>>((const float4*)x, (bf16x4*)xb, BS_ * D_ / 4);
  // 2. transpose+convert q/k/v weights (wo later — its slot holds partB)
  k_transpose_cvt<<<dim3(D_ / 32, D_ / 32), tb, 0, stream>>>(wq, wqkvt, D_, D_);
  k_transpose_cvt<<<dim3(32, D_ / 32), tb, 0, stream>>>(wk, wqkvt + (size_t)D_ * D_, D_, NKV_ * HD_);
  k_transpose_cvt<<<dim3(32, D_ / 32), tb, 0, stream>>>(wv, wqkvt + (size_t)(D_ + NKV_ * HD_) * D_, D_, NKV_ * HD_);
  // 3a. Q projection: NF=4, 16x16 = 256 blocks = 1 clean round
  k_gemm8p<bf16_t><<<dim3(BS_ / 256, D_ / 256, 1), 512, 0, stream>>>(
      xb, wqkvt, qc, BS_, D_, D_, D_, 0);
  // 3b. KV projection, split-K=2: grid (16,8,2) = 256 blocks = 1 clean round.
  //     z=0: K in [0,2048) -> partA; z=1: K in [2048,4096) -> partB.
  k_gemm8p<bf16_t><<<dim3(BS_ / 256, 2048 / 256, 2), 512, 0, stream>>>(
      xb, wqkvt + (size_t)D_ * D_, partA, BS_, 2048, D_, 2048,
      (long long)(partB - partA));
  // 4. RoPE + reorder (Q pre-scaled into log2 domain); K/V sum the two parts
  k_rope<<<BS_ * NH_ * 64 / 256, 256, 0, stream>>>(qc, (const bf16_t*)nullptr,
      fcos, fsin, qrope, NH_, D_, QSCALE);
  k_rope<<<BS_ * NKV_ * 64 / 256, 256, 0, stream>>>(partA, partB,
      fcos, fsin, krope, NKV_, 2048, 1.0f);
  k_vtrans<<<dim3(S_ / 32, HD_ / 32, B_ * NKV_), tb, 0, stream>>>(partA, partB, vtr);
  // 5. transpose wo (partB now dead)
  k_transpose_cvt<<<dim3(D_ / 32, D_ / 32), tb, 0, stream>>>(wo, wot, D_, D_);
  // 6. flash attention (round-10 config: 256 thr, grid (16,32,2))
  k_flash<<<dim3(S_ / 128, NH_, B_), 256, 0, stream>>>(qrope, krope, vtr, ctx);
  // 7. output projection -> f32 out: 256 blocks = 1 round
  k_gemm8p<float><<<dim3(BS_ / 256, D_ / 256, 1), 512, 0, stream>>>(
      ctx, wot, out, BS_, D_, D_, D_, 0);
}

// Round 14
// 569.186 us; speedup vs baseline: 1.6779x; 1.0104x over previous
//
#include <hip/hip_runtime.h>
#include <hip/hip_bf16.h>
#include <cstdint>

#define B_   2
#define S_   2048
#define D_   4096
#define NH_  32
#define NKV_ 8
#define HD_  128
#define BS_  (B_*S_)      // 4096 rows
#define NQK_ 6144

typedef __bf16 bf16_t;
typedef __bf16 bf16x8 __attribute__((ext_vector_type(8)));
typedef __bf16 bf16x4 __attribute__((ext_vector_type(4)));
typedef __bf16 bf16x2 __attribute__((ext_vector_type(2)));
typedef float  f32x4  __attribute__((ext_vector_type(4)));
typedef float  f32x16 __attribute__((ext_vector_type(16)));
typedef unsigned uint32x4 __attribute__((ext_vector_type(4)));

typedef const __attribute__((address_space(1))) void* gas_ptr;
typedef __attribute__((address_space(3))) void* las_ptr;

__device__ __forceinline__ void gload_lds16(const void* g, void* l) {
  __builtin_amdgcn_global_load_lds((gas_ptr)g, (las_ptr)l, 16, 0, 0);
}

__device__ __forceinline__ float exp2_fast(float x) {   // v_exp_f32 = 2^x
  float r;
  asm("v_exp_f32 %0, %1" : "=v"(r) : "v"(x));
  return r;
}

__device__ __forceinline__ unsigned cvt_pk_bf16(float a, float b) {
  unsigned r;
  asm("v_cvt_pk_bf16_f32 %0, %1, %2" : "=v"(r) : "v"(a), "v"(b));
  return r;
}

#define LD8(p) (*(const bf16x8*)(p))
#define MFMA(a, b, c) __builtin_amdgcn_mfma_f32_16x16x32_bf16(a, b, c, 0, 0, 0)
#define MFMA32(a, b, c) __builtin_amdgcn_mfma_f32_32x32x16_bf16(a, b, c, 0, 0, 0)

// ---------------- f32 -> bf16 convert (vectorized) ----------------
__global__ __launch_bounds__(256) void k_cvt(const float4* __restrict__ in,
                                             bf16x4* __restrict__ out, int n4) {
  int i = blockIdx.x * 256 + threadIdx.x;
  if (i >= n4) return;
  float4 v = in[i];
  bf16x4 o = { (bf16_t)v.x, (bf16_t)v.y, (bf16_t)v.z, (bf16_t)v.w };
  out[i] = o;
}

// ---------------- w[K][N] f32 -> wt[N][K] bf16 (tiled transpose) ----------------
__global__ __launch_bounds__(256) void k_transpose_cvt(const float* __restrict__ w,
                                                       bf16_t* __restrict__ wt,
                                                       int K, int N) {
  __shared__ float tile[32][33];
  int n0 = blockIdx.x * 32, k0 = blockIdx.y * 32;
  int tx = threadIdx.x, ty = threadIdx.y;   // 32x8
#pragma unroll
  for (int i = 0; i < 4; i++)
    tile[ty + 8*i][tx] = w[(size_t)(k0 + ty + 8*i) * N + n0 + tx];
  __syncthreads();
#pragma unroll
  for (int i = 0; i < 4; i++)
    wt[(size_t)(n0 + ty + 8*i) * K + k0 + tx] = (bf16_t)tile[tx][ty + 8*i];
}

// ---------------- 256x256 NT GEMM — 4-phase/K-tile template (NF=4) ------------
// Split-K via blockIdx.z (kOff = z*KL, C += z*zsC). See round-13 notes.
template <typename CT>
__global__ __launch_bounds__(512, 2) void k_gemm8p(const bf16_t* __restrict__ A,
                                                   const bf16_t* __restrict__ Bt,
                                                   CT* __restrict__ C,
                                                   int M, int N, int K, int KL,
                                                   long long zsC) {
  constexpr int NF = 4;
  __shared__ __align__(16) bf16_t As[2][256 * 64];       // 2 x 32 KB
  __shared__ __align__(16) bf16_t Bs[2][NF * 64 * 64];   // 2 x 32 KB
  const int tid = threadIdx.x;
  const int l = tid & 63, w = tid >> 6;
  const int lr = l & 15, lg = l >> 4;
  const int wm = w >> 2, wn = w & 3;       // 2M x 4N wave grid

  const int bm = blockIdx.x, bn = blockIdx.y;
  const int kOff = blockIdx.z * KL;

  const bf16_t* Ab = A  + (size_t)bm * 256 * K + kOff;
  const bf16_t* Bb = Bt + (size_t)bn * 256 * K + kOff;
  C += (long long)blockIdx.z * zsC;

  int st_row[4], st_col[4], st_dst[4];
#pragma unroll
  for (int j = 0; j < 4; j++) {
    int o = (j * 512 + tid) * 16;          // byte offset
    int row = o >> 7, cb = o & 127;        // 128B rows
    st_row[j] = row;
    st_col[j] = (cb ^ ((row & 7) << 4)) >> 1;
    st_dst[j] = o >> 1;
  }

  int aoff[8], boff[NF];
#pragma unroll
  for (int m = 0; m < 8; m++) {
    int r = wm * 128 + m * 16 + lr;
    aoff[m] = r * 64 + (((lg * 16) ^ ((r & 7) << 4)) >> 1);
  }
#pragma unroll
  for (int n = 0; n < NF; n++) {
    int r = wn * 64 + n * 16 + lr;
    boff[n] = r * 64 + (((lg * 16) ^ ((r & 7) << 4)) >> 1);
  }

  f32x4 acc[8][NF];
#pragma unroll
  for (int m = 0; m < 8; m++)
#pragma unroll
    for (int n = 0; n < NF; n++) acc[m][n] = f32x4{0.f, 0.f, 0.f, 0.f};

  auto stageA = [&](int k, int h) {       // half h: 128 rows, 2 loads
    const int kt = k << 6;
    const int rof = h << 7;
#pragma unroll
    for (int j = 0; j < 2; j++)
      gload_lds16(Ab + (size_t)(st_row[j] + rof) * K + kt + st_col[j],
                  &As[k & 1][0] + (rof << 6) + st_dst[j]);
  };
  auto stageB = [&](int k) {              // full B tile: 256 rows, 4 loads
    const int kt = k << 6;
#pragma unroll
    for (int j = 0; j < NF; j++)
      gload_lds16(Bb + (size_t)st_row[j] * K + kt + st_col[j],
                  &Bs[k & 1][0] + st_dst[j]);
  };

  const int NT = KL >> 6;
  stageA(0, 0); stageA(0, 1); stageB(0); stageB(1);
  asm volatile("s_waitcnt vmcnt(4)" ::: "memory");
  __builtin_amdgcn_s_barrier();

  for (int k = 0; k < NT; ++k) {
    const bf16_t* Ap = &As[k & 1][0];
    const bf16_t* Bp = &Bs[k & 1][0];
    const bool s1 = (k + 1 < NT), s2 = (k + 2 < NT);
    bf16x8 bfr[NF], a[4];

    // ---- P0: b kk0 + a[0..3] kk0 ; stage A-half0(k+1) ----
#pragma unroll
    for (int n = 0; n < NF; n++) bfr[n] = LD8(Bp + boff[n]);
#pragma unroll
    for (int m = 0; m < 4; m++) a[m] = LD8(Ap + aoff[m]);
    if (s1) stageA(k + 1, 0);
    __builtin_amdgcn_s_barrier();
    asm volatile("s_waitcnt lgkmcnt(0)" ::: "memory");
    __builtin_amdgcn_s_setprio(1);
#pragma unroll
    for (int m = 0; m < 4; m++)
#pragma unroll
      for (int n = 0; n < NF; n++)
        acc[m][n] = MFMA(a[m], bfr[n], acc[m][n]);
    __builtin_amdgcn_s_setprio(0);
    __builtin_amdgcn_s_barrier();

    // ---- P1: a[4..7] kk0 ; stage A-half1(k+1) ----
#pragma unroll
    for (int m = 0; m < 4; m++) a[m] = LD8(Ap + aoff[m + 4]);
    if (s1) stageA(k + 1, 1);
    __builtin_amdgcn_s_barrier();
    asm volatile("s_waitcnt lgkmcnt(0)" ::: "memory");
    __builtin_amdgcn_s_setprio(1);
#pragma unroll
    for (int m = 0; m < 4; m++)
#pragma unroll
      for (int n = 0; n < NF; n++)
        acc[m + 4][n] = MFMA(a[m], bfr[n], acc[m + 4][n]);
    __builtin_amdgcn_s_setprio(0);
    __builtin_amdgcn_s_barrier();

    // ---- P2: b kk1 + a[0..3] kk1 ----
#pragma unroll
    for (int n = 0; n < NF; n++) bfr[n] = LD8(Bp + (boff[n] ^ 32));
#pragma unroll
    for (int m = 0; m < 4; m++) a[m] = LD8(Ap + (aoff[m] ^ 32));
    __builtin_amdgcn_s_barrier();
    asm volatile("s_waitcnt lgkmcnt(0)" ::: "memory");
    __builtin_amdgcn_s_setprio(1);
#pragma unroll
    for (int m = 0; m < 4; m++)
#pragma unroll
      for (int n = 0; n < NF; n++)
        acc[m][n] = MFMA(a[m], bfr[n], acc[m][n]);
    __builtin_amdgcn_s_setprio(0);
    __builtin_amdgcn_s_barrier();

    // ---- P3: a[4..7] kk1 ; stage B(k+2) ; boundary vmcnt ----
#pragma unroll
    for (int m = 0; m < 4; m++) a[m] = LD8(Ap + (aoff[m + 4] ^ 32));
    if (s2) {
      stageB(k + 2);
      asm volatile("s_waitcnt vmcnt(4)" ::: "memory");
    } else if (s1) {
      asm volatile("s_waitcnt vmcnt(0)" ::: "memory");
    }
    __builtin_amdgcn_s_barrier();
    asm volatile("s_waitcnt lgkmcnt(0)" ::: "memory");
    __builtin_amdgcn_s_setprio(1);
#pragma unroll
    for (int m = 0; m < 4; m++)
#pragma unroll
      for (int n = 0; n < NF; n++)
        acc[m + 4][n] = MFMA(a[m], bfr[n], acc[m + 4][n]);
    __builtin_amdgcn_s_setprio(0);
    __builtin_amdgcn_s_barrier();
  }

#pragma unroll
  for (int m = 0; m < 8; m++) {
    int row0 = bm * 256 + wm * 128 + m * 16 + lg * 4;
#pragma unroll
    for (int n = 0; n < NF; n++) {
      int col = bn * 256 + wn * 64 + n * 16 + lr;
#pragma unroll
      for (int i = 0; i < 4; i++)
        C[(size_t)(row0 + i) * N + col] = (CT)acc[m][n][i];
    }
  }
}

// ---------------- RoPE + head-major reorder (optionally sums two parts) -------
__global__ __launch_bounds__(256) void k_rope(const bf16_t* __restrict__ s1,
                                              const bf16_t* __restrict__ s2,
                                              const float* __restrict__ fcos,
                                              const float* __restrict__ fsin,
                                              bf16_t* __restrict__ dst,
                                              int nheads, int stride, float mul) {
  int idx = blockIdx.x * 256 + threadIdx.x;
  int p = idx & 63;
  int h = (idx >> 6) % nheads;
  int bs = idx / (64 * nheads);
  int s = bs & (S_ - 1);
  int b = bs >> 11;
  size_t off = (size_t)bs * stride + h * HD_ + 2 * p;
  bf16x2 ab = *(const bf16x2*)(s1 + off);
  float a = (float)ab[0], bb = (float)ab[1];
  if (s2) {
    bf16x2 ab2 = *(const bf16x2*)(s2 + off);
    a += (float)ab2[0]; bb += (float)ab2[1];
  }
  float c = fcos[s * 64 + p], sn = fsin[s * 64 + p];
  bf16x2 o = { (bf16_t)((a * c - bb * sn) * mul), (bf16_t)((a * sn + bb * c) * mul) };
  *(bf16x2*)(dst + ((((size_t)b * nheads + h) * S_ + s) * HD_) + 2 * p) = o;
}

// ---------------- V transpose from KV parts: -> vt[B][NKV][HD][S] -------------
__global__ __launch_bounds__(256) void k_vtrans(const bf16_t* __restrict__ pA,
                                                const bf16_t* __restrict__ pB,
                                                bf16_t* __restrict__ vtr) {
  __shared__ bf16_t tile[32][33];
  int s0 = blockIdx.x * 32, d0 = blockIdx.y * 32, z = blockIdx.z;  // z = b*NKV+kvh
  int b = z >> 3, kvh = z & 7;
  int tx = threadIdx.x, ty = threadIdx.y;
#pragma unroll
  for (int i = 0; i < 4; i++) {
    size_t off = (size_t)(b * S_ + s0 + ty + 8*i) * 2048 + 1024 + kvh * HD_ + d0 + tx;
    tile[ty + 8*i][tx] = (bf16_t)((float)pA[off] + (float)pB[off]);
  }
  __syncthreads();
#pragma unroll
  for (int i = 0; i < 4; i++)
    vtr[((size_t)z * HD_ + d0 + ty + 8*i) * S_ + s0 + tx] = tile[tx][ty + 8*i];
}

// ---------------- Flash attention: 32x32x16 MFMA, in-register softmax ---------
// grid (S/128, NH, B), 256 thr (4 waves). Wave w owns 32 q-rows.
// Swapped QK^T: acc_s[kb] = MFMA32(K-frag, Q-frag) -> lane (q=l&31,h=l>>5)
// holds S^T[k][q], k = 32kb + (r&3)+8*(r>>2)+4h. mR/lR = per-lane scalars.
// P->PV B-frag: per kstep s2, pack Wlo/Whi via cvt_pk; ONE permlane32_swap per
// word pair gives both needed words (dst-high <-> src-low exchange).
// PV: acc_o[db] = MFMA32(V^T-frag, P-frag) = O^T[d][q]; lR divide lane-local.
// Epilogue: LDS transpose (reuse Ks, q-swizzled) -> coalesced ctx writes.
#define KVBLK 64
#define SM_THR 12.0f
__global__ __launch_bounds__(256, 2) void k_flash(const bf16_t* __restrict__ qr,
                                                  const bf16_t* __restrict__ kr,
                                                  const bf16_t* __restrict__ vt,
                                                  bf16_t* __restrict__ ctx) {
  __shared__ __align__(16) bf16_t Ks[2][KVBLK * HD_];   // 2 x 16 KB [s][d] swz
  __shared__ __align__(16) bf16_t Vs[2][HD_ * KVBLK];   // 2 x 16 KB [d][s] swz
  const int tid = threadIdx.x;
  const int l = tid & 63, w = tid >> 6;
  const int q5 = l & 31, h = l >> 5;
  const int qb = blockIdx.x, hh = blockIdx.y, b = blockIdx.z;
  const int kvh = hh >> 2;   // NREP=4

  const bf16_t* qbase = qr + (((size_t)b * NH_ + hh) * S_ + qb * 128 + w * 32) * HD_;
  const bf16_t* kbase = kr + (((size_t)b * NKV_ + kvh) * S_) * HD_;
  const bf16_t* vbase = vt + (((size_t)b * NKV_ + kvh) * HD_) * S_;

  // Q fragments (B-operand): qf[s]: Q[q5][16s + 8h + 0..7], s=0..7
  bf16x8 qf[8];
#pragma unroll
  for (int s = 0; s < 8; s++)
    qf[s] = LD8(qbase + q5 * HD_ + s * 16 + h * 8);

  f32x16 acco[4];
#pragma unroll
  for (int db = 0; db < 4; db++)
#pragma unroll
    for (int r = 0; r < 16; r++) acco[db][r] = 0.f;
  float mR = -1e30f, lR = 0.f;

  auto stage = [&](int bu, int t) {
    const int kb = t * KVBLK;
#pragma unroll
    for (int j = 0; j < 4; j++) {
      int o_ = (tid + 256 * j) * 16;
      int row = o_ >> 8, cb = o_ & 255;
      int scb = cb ^ ((row & 7) << 4);
      gload_lds16(kbase + (size_t)(kb + row) * HD_ + (scb >> 1),
                  &Ks[bu][0] + (o_ >> 1));
    }
#pragma unroll
    for (int j = 0; j < 4; j++) {
      int o_ = (tid + 256 * j) * 16;
      int row = o_ >> 7, cb = o_ & 127;
      int scb = cb ^ ((row & 7) << 4);
      gload_lds16(vbase + (size_t)row * S_ + kb + (scb >> 1),
                  &Vs[bu][0] + (o_ >> 1));
    }
  };

  const int nt = S_ / KVBLK;
  stage(0, 0);
  __syncthreads();
  int buf = 0;

  for (int t = 0; t < nt; t++) {
    if (t + 1 < nt) stage(buf ^ 1, t + 1);
    const bf16_t* Kb = &Ks[buf][0];
    const bf16_t* Vb = &Vs[buf][0];

    // QK^T: acc_s[kb] over 8 hd-steps
    f32x16 accs[2];
#pragma unroll
    for (int kb = 0; kb < 2; kb++)
#pragma unroll
      for (int r = 0; r < 16; r++) accs[kb][r] = 0.f;
    __builtin_amdgcn_s_setprio(1);
#pragma unroll
    for (int s = 0; s < 8; s++) {
#pragma unroll
      for (int kb = 0; kb < 2; kb++) {
        int r = kb * 32 + q5;
        int cb = (32 * s + 16 * h) ^ ((r & 7) << 4);
        bf16x8 kf = LD8(Kb + (r << 7) + (cb >> 1));
        accs[kb] = MFMA32(kf, qf[s], accs[kb]);
      }
    }
    __builtin_amdgcn_s_setprio(0);

    // softmax: per-lane scalar stats (lane's 32 scores all belong to q=q5)
    float lm = accs[0][0];
#pragma unroll
    for (int kb = 0; kb < 2; kb++)
#pragma unroll
      for (int r = 0; r < 16; r++)
        if (kb | r) lm = fmaxf(lm, accs[kb][r]);
    if (!__all(lm - mR <= SM_THR)) {     // trigger: tile 0 + rare growth
      float fm = fmaxf(lm, __shfl_xor(lm, 32));
      float mnew = fmaxf(mR, fm);
      float alpha = exp2_fast(mR - mnew);
      mR = mnew;
      lR *= alpha;
#pragma unroll
      for (int db = 0; db < 4; db++)
#pragma unroll
        for (int r = 0; r < 16; r++) acco[db][r] *= alpha;
    }
    // P = 2^(sc-mR); pack + permlane-exchange into PV B-frags
    float psum = 0.f;
    bf16x8 pb[4];
#pragma unroll
    for (int s2 = 0; s2 < 4; s2++) {
      const int kb = s2 >> 1, rb = (s2 & 1) * 8;
      float pv[8];
#pragma unroll
      for (int j = 0; j < 8; j++) {
        pv[j] = exp2_fast(accs[kb][rb + j] - mR);
        psum += pv[j];
      }
      unsigned wlo0 = cvt_pk_bf16(pv[0], pv[1]);
      unsigned wlo1 = cvt_pk_bf16(pv[2], pv[3]);
      unsigned whi0 = cvt_pk_bf16(pv[4], pv[5]);
      unsigned whi1 = cvt_pk_bf16(pv[6], pv[7]);
      asm volatile("v_permlane32_swap_b32 %0, %1" : "+v"(wlo0), "+v"(whi0));
      asm volatile("v_permlane32_swap_b32 %0, %1" : "+v"(wlo1), "+v"(whi1));
      uint32x4 wv = { wlo0, wlo1, whi0, whi1 };
      pb[s2] = __builtin_bit_cast(bf16x8, wv);
    }
    psum += __shfl_xor(psum, 32);
    lR += psum;

    // PV: acc_o[db] += V^T-frag x P-frag
    __builtin_amdgcn_s_setprio(1);
#pragma unroll
    for (int s2 = 0; s2 < 4; s2++) {
#pragma unroll
      for (int db = 0; db < 4; db++) {
        int rv = db * 32 + q5;
        int cb = (32 * s2 + 16 * h) ^ ((rv & 7) << 4);
        bf16x8 vf = LD8(Vb + (rv << 6) + (cb >> 1));
        acco[db] = MFMA32(vf, pb[s2], acco[db]);
      }
    }
    __builtin_amdgcn_s_setprio(0);
    __syncthreads();
    buf ^= 1;
  }

  // epilogue: normalize + transpose O^T[d][q] -> ctx[q][d] via LDS (reuse Ks)
  float inv = 1.0f / lR;
  bf16_t* tb = &Ks[0][0] + w * (32 * 128);   // per-wave [32 q][128 d] region
#pragma unroll
  for (int db = 0; db < 4; db++)
#pragma unroll
    for (int rp = 0; rp < 8; rp++) {
      int r = 2 * rp;
      int d0 = (r & 3) + 8 * (r >> 2) + 4 * h + 32 * db;
      unsigned word = cvt_pk_bf16(acco[db][r] * inv, acco[db][r + 1] * inv);
      int cbyte = (d0 * 2) ^ ((q5 & 7) << 4);
      *(unsigned*)((char*)tb + q5 * 256 + cbyte) = word;
    }
  __syncthreads();
#pragma unroll
  for (int it = 0; it < 8; it++) {
    int gid = it * 256 + tid;                 // granule id: 4w x 32q x 16g
    int wv = gid >> 9, rem = gid & 511;
    int qq = rem >> 4, g = rem & 15;
    int cbyte = (g * 16) ^ ((qq & 7) << 4);
    bf16x8 v = LD8((const bf16_t*)((const char*)(&Ks[0][0] + wv * (32 * 128)) + qq * 256 + cbyte));
    int srow = qb * 128 + wv * 32 + qq;
    *(bf16x8*)(ctx + ((size_t)(b * S_ + srow)) * D_ + hh * HD_ + g * 8) = v;
  }
}

// ---------------- launch ----------------
extern "C" void kernel_launch(void* const* d_in, const int* in_sizes, int n_in,
                              void* d_out, int out_size, void* d_ws, size_t ws_size,
                              hipStream_t stream) {
  const float* x    = (const float*)d_in[0];
  const float* wq   = (const float*)d_in[1];
  const float* wk   = (const float*)d_in[2];
  const float* wv   = (const float*)d_in[3];
  const float* wo   = (const float*)d_in[4];
  const float* fcos = (const float*)d_in[5];
  const float* fsin = (const float*)d_in[6];
  float* out = (float*)d_out;

  // workspace layout (160 MB, aliased) — see round-13 notes
  const size_t MB = 1u << 20;
  char* p = (char*)d_ws;
  bf16_t* xb    = (bf16_t*)p;
  bf16_t* wqkvt = (bf16_t*)(p + 32 * MB);
  bf16_t* wot   = (bf16_t*)(p + 80 * MB);
  bf16_t* qc    = (bf16_t*)(p + 112 * MB);
  bf16_t* partA = (bf16_t*)(p + 144 * MB);
  bf16_t* partB = wot;
  bf16_t* qrope = xb;
  bf16_t* krope = wqkvt;
  bf16_t* vtr   = wqkvt + (size_t)BS_ * NKV_ * HD_;
  bf16_t* ctx   = qc;

  // Q pre-scale: log2(e) / sqrt(HD)  (scores land in log2 domain)
  const float QSCALE = (float)(0.08838834764831845 * 1.4426950408889634);

  dim3 tb(32, 8);
  // 1. x -> bf16
  k_cvt<<<BS_ * D_ / 1024, 256, 0, stream>>>((const float4*)x, (bf16x4*)xb, BS_ * D_ / 4);
  // 2. transpose+convert q/k/v weights (wo later — its slot holds partB)
  k_transpose_cvt<<<dim3(D_ / 32, D_ / 32), tb, 0, stream>>>(wq, wqkvt, D_, D_);
  k_transpose_cvt<<<dim3(32, D_ / 32), tb, 0, stream>>>(wk, wqkvt + (size_t)D_ * D_, D_, NKV_ * HD_);
  k_transpose_cvt<<<dim3(32, D_ / 32), tb, 0, stream>>>(wv, wqkvt + (size_t)(D_ + NKV_ * HD_) * D_, D_, NKV_ * HD_);
  // 3a. Q projection: NF=4, 16x16 = 256 blocks = 1 clean round
  k_gemm8p<bf16_t><<<dim3(BS_ / 256, D_ / 256, 1), 512, 0, stream>>>(
      xb, wqkvt, qc, BS_, D_, D_, D_, 0);
  // 3b. KV projection, split-K=2: grid (16,8,2) = 256 blocks = 1 clean round
  k_gemm8p<bf16_t><<<dim3(BS_ / 256, 2048 / 256, 2), 512, 0, stream>>>(
      xb, wqkvt + (size_t)D_ * D_, partA, BS_, 2048, D_, 2048,
      (long long)(partB - partA));
  // 4. RoPE + reorder; K/V sum the two split-K parts
  k_rope<<<BS_ * NH_ * 64 / 256, 256, 0, stream>>>(qc, (const bf16_t*)nullptr,
      fcos, fsin, qrope, NH_, D_, QSCALE);
  k_rope<<<BS_ * NKV_ * 64 / 256, 256, 0, stream>>>(partA, partB,
      fcos, fsin, krope, NKV_, 2048, 1.0f);
  k_vtrans<<<dim3(S_ / 32, HD_ / 32, B_ * NKV_), tb, 0, stream>>>(partA, partB, vtr);
  // 5. transpose wo (partB now dead)
  k_transpose_cvt<<<dim3(D_ / 32, D_ / 32), tb, 0, stream>>>(wo, wot, D_, D_);
  // 6. flash attention (32x32 MFMA version)
  k_flash<<<dim3(S_ / 128, NH_, B_), 256, 0, stream>>>(qrope, krope, vtr, ctx);
  // 7. output projection -> f32 out: 256 blocks = 1 round
  k_gemm8p<float><<<dim3(BS_ / 256, D_ / 256, 1), 512, 0, stream>>>(
      ctx, wot, out, BS_, D_, D_, D_, 0);
}

// Round 15
// 567.867 us; speedup vs baseline: 1.6818x; 1.0023x over previous
//
#include <hip/hip_runtime.h>
#include <hip/hip_bf16.h>
#include <cstdint>

#define B_   2
#define S_   2048
#define D_   4096
#define NH_  32
#define NKV_ 8
#define HD_  128
#define BS_  (B_*S_)      // 4096 rows
#define NQK_ 6144

typedef __bf16 bf16_t;
typedef __bf16 bf16x8 __attribute__((ext_vector_type(8)));
typedef __bf16 bf16x4 __attribute__((ext_vector_type(4)));
typedef __bf16 bf16x2 __attribute__((ext_vector_type(2)));
typedef float  f32x4  __attribute__((ext_vector_type(4)));
typedef float  f32x16 __attribute__((ext_vector_type(16)));
typedef unsigned uint32x4 __attribute__((ext_vector_type(4)));

typedef const __attribute__((address_space(1))) void* gas_ptr;
typedef __attribute__((address_space(3))) void* las_ptr;

__device__ __forceinline__ void gload_lds16(const void* g, void* l) {
  __builtin_amdgcn_global_load_lds((gas_ptr)g, (las_ptr)l, 16, 0, 0);
}

__device__ __forceinline__ float exp2_fast(float x) {   // v_exp_f32 = 2^x
  float r;
  asm("v_exp_f32 %0, %1" : "=v"(r) : "v"(x));
  return r;
}

__device__ __forceinline__ unsigned cvt_pk_bf16(float a, float b) {
  unsigned r;
  asm("v_cvt_pk_bf16_f32 %0, %1, %2" : "=v"(r) : "v"(a), "v"(b));
  return r;
}

#define LD8(p) (*(const bf16x8*)(p))
#define MFMA(a, b, c) __builtin_amdgcn_mfma_f32_16x16x32_bf16(a, b, c, 0, 0, 0)
#define MFMA32(a, b, c) __builtin_amdgcn_mfma_f32_32x32x16_bf16(a, b, c, 0, 0, 0)

// ---------------- f32 -> bf16 convert (vectorized) ----------------
__global__ __launch_bounds__(256) void k_cvt(const float4* __restrict__ in,
                                             bf16x4* __restrict__ out, int n4) {
  int i = blockIdx.x * 256 + threadIdx.x;
  if (i >= n4) return;
  float4 v = in[i];
  bf16x4 o = { (bf16_t)v.x, (bf16_t)v.y, (bf16_t)v.z, (bf16_t)v.w };
  out[i] = o;
}

// ---------------- w[K][N] f32 -> wt[N][K] bf16 (tiled transpose) ----------------
__global__ __launch_bounds__(256) void k_transpose_cvt(const float* __restrict__ w,
                                                       bf16_t* __restrict__ wt,
                                                       int K, int N) {
  __shared__ float tile[32][33];
  int n0 = blockIdx.x * 32, k0 = blockIdx.y * 32;
  int tx = threadIdx.x, ty = threadIdx.y;   // 32x8
#pragma unroll
  for (int i = 0; i < 4; i++)
    tile[ty + 8*i][tx] = w[(size_t)(k0 + ty + 8*i) * N + n0 + tx];
  __syncthreads();
#pragma unroll
  for (int i = 0; i < 4; i++)
    wt[(size_t)(n0 + ty + 8*i) * K + k0 + tx] = (bf16_t)tile[tx][ty + 8*i];
}

// ---------------- 256x256 NT GEMM — 4-phase/K-tile template (NF=4) ------------
// Split-K via blockIdx.z (kOff = z*KL, C += z*zsC). See round-13 notes.
template <typename CT>
__global__ __launch_bounds__(512, 2) void k_gemm8p(const bf16_t* __restrict__ A,
                                                   const bf16_t* __restrict__ Bt,
                                                   CT* __restrict__ C,
                                                   int M, int N, int K, int KL,
                                                   long long zsC) {
  constexpr int NF = 4;
  __shared__ __align__(16) bf16_t As[2][256 * 64];       // 2 x 32 KB
  __shared__ __align__(16) bf16_t Bs[2][NF * 64 * 64];   // 2 x 32 KB
  const int tid = threadIdx.x;
  const int l = tid & 63, w = tid >> 6;
  const int lr = l & 15, lg = l >> 4;
  const int wm = w >> 2, wn = w & 3;       // 2M x 4N wave grid

  const int bm = blockIdx.x, bn = blockIdx.y;
  const int kOff = blockIdx.z * KL;

  const bf16_t* Ab = A  + (size_t)bm * 256 * K + kOff;
  const bf16_t* Bb = Bt + (size_t)bn * 256 * K + kOff;
  C += (long long)blockIdx.z * zsC;

  int st_row[4], st_col[4], st_dst[4];
#pragma unroll
  for (int j = 0; j < 4; j++) {
    int o = (j * 512 + tid) * 16;          // byte offset
    int row = o >> 7, cb = o & 127;        // 128B rows
    st_row[j] = row;
    st_col[j] = (cb ^ ((row & 7) << 4)) >> 1;
    st_dst[j] = o >> 1;
  }

  int aoff[8], boff[NF];
#pragma unroll
  for (int m = 0; m < 8; m++) {
    int r = wm * 128 + m * 16 + lr;
    aoff[m] = r * 64 + (((lg * 16) ^ ((r & 7) << 4)) >> 1);
  }
#pragma unroll
  for (int n = 0; n < NF; n++) {
    int r = wn * 64 + n * 16 + lr;
    boff[n] = r * 64 + (((lg * 16) ^ ((r & 7) << 4)) >> 1);
  }

  f32x4 acc[8][NF];
#pragma unroll
  for (int m = 0; m < 8; m++)
#pragma unroll
    for (int n = 0; n < NF; n++) acc[m][n] = f32x4{0.f, 0.f, 0.f, 0.f};

  auto stageA = [&](int k, int h) {       // half h: 128 rows, 2 loads
    const int kt = k << 6;
    const int rof = h << 7;
#pragma unroll
    for (int j = 0; j < 2; j++)
      gload_lds16(Ab + (size_t)(st_row[j] + rof) * K + kt + st_col[j],
                  &As[k & 1][0] + (rof << 6) + st_dst[j]);
  };
  auto stageB = [&](int k) {              // full B tile: 256 rows, 4 loads
    const int kt = k << 6;
#pragma unroll
    for (int j = 0; j < NF; j++)
      gload_lds16(Bb + (size_t)st_row[j] * K + kt + st_col[j],
                  &Bs[k & 1][0] + st_dst[j]);
  };

  const int NT = KL >> 6;
  stageA(0, 0); stageA(0, 1); stageB(0); stageB(1);
  asm volatile("s_waitcnt vmcnt(4)" ::: "memory");
  __builtin_amdgcn_s_barrier();

  for (int k = 0; k < NT; ++k) {
    const bf16_t* Ap = &As[k & 1][0];
    const bf16_t* Bp = &Bs[k & 1][0];
    const bool s1 = (k + 1 < NT), s2 = (k + 2 < NT);
    bf16x8 bfr[NF], a[4];

    // ---- P0: b kk0 + a[0..3] kk0 ; stage A-half0(k+1) ----
#pragma unroll
    for (int n = 0; n < NF; n++) bfr[n] = LD8(Bp + boff[n]);
#pragma unroll
    for (int m = 0; m < 4; m++) a[m] = LD8(Ap + aoff[m]);
    if (s1) stageA(k + 1, 0);
    __builtin_amdgcn_s_barrier();
    asm volatile("s_waitcnt lgkmcnt(0)" ::: "memory");
    __builtin_amdgcn_s_setprio(1);
#pragma unroll
    for (int m = 0; m < 4; m++)
#pragma unroll
      for (int n = 0; n < NF; n++)
        acc[m][n] = MFMA(a[m], bfr[n], acc[m][n]);
    __builtin_amdgcn_s_setprio(0);
    __builtin_amdgcn_s_barrier();

    // ---- P1: a[4..7] kk0 ; stage A-half1(k+1) ----
#pragma unroll
    for (int m = 0; m < 4; m++) a[m] = LD8(Ap + aoff[m + 4]);
    if (s1) stageA(k + 1, 1);
    __builtin_amdgcn_s_barrier();
    asm volatile("s_waitcnt lgkmcnt(0)" ::: "memory");
    __builtin_amdgcn_s_setprio(1);
#pragma unroll
    for (int m = 0; m < 4; m++)
#pragma unroll
      for (int n = 0; n < NF; n++)
        acc[m + 4][n] = MFMA(a[m], bfr[n], acc[m + 4][n]);
    __builtin_amdgcn_s_setprio(0);
    __builtin_amdgcn_s_barrier();

    // ---- P2: b kk1 + a[0..3] kk1 ----
#pragma unroll
    for (int n = 0; n < NF; n++) bfr[n] = LD8(Bp + (boff[n] ^ 32));
#pragma unroll
    for (int m = 0; m < 4; m++) a[m] = LD8(Ap + (aoff[m] ^ 32));
    __builtin_amdgcn_s_barrier();
    asm volatile("s_waitcnt lgkmcnt(0)" ::: "memory");
    __builtin_amdgcn_s_setprio(1);
#pragma unroll
    for (int m = 0; m < 4; m++)
#pragma unroll
      for (int n = 0; n < NF; n++)
        acc[m][n] = MFMA(a[m], bfr[n], acc[m][n]);
    __builtin_amdgcn_s_setprio(0);
    __builtin_amdgcn_s_barrier();

    // ---- P3: a[4..7] kk1 ; stage B(k+2) ; boundary vmcnt ----
#pragma unroll
    for (int m = 0; m < 4; m++) a[m] = LD8(Ap + (aoff[m + 4] ^ 32));
    if (s2) {
      stageB(k + 2);
      asm volatile("s_waitcnt vmcnt(4)" ::: "memory");
    } else if (s1) {
      asm volatile("s_waitcnt vmcnt(0)" ::: "memory");
    }
    __builtin_amdgcn_s_barrier();
    asm volatile("s_waitcnt lgkmcnt(0)" ::: "memory");
    __builtin_amdgcn_s_setprio(1);
#pragma unroll
    for (int m = 0; m < 4; m++)
#pragma unroll
      for (int n = 0; n < NF; n++)
        acc[m + 4][n] = MFMA(a[m], bfr[n], acc[m + 4][n]);
    __builtin_amdgcn_s_setprio(0);
    __builtin_amdgcn_s_barrier();
  }

#pragma unroll
  for (int m = 0; m < 8; m++) {
    int row0 = bm * 256 + wm * 128 + m * 16 + lg * 4;
#pragma unroll
    for (int n = 0; n < NF; n++) {
      int col = bn * 256 + wn * 64 + n * 16 + lr;
#pragma unroll
      for (int i = 0; i < 4; i++)
        C[(size_t)(row0 + i) * N + col] = (CT)acc[m][n][i];
    }
  }
}

// ---------------- RoPE + head-major reorder (optionally sums two parts) -------
__global__ __launch_bounds__(256) void k_rope(const bf16_t* __restrict__ s1,
                                              const bf16_t* __restrict__ s2,
                                              const float* __restrict__ fcos,
                                              const float* __restrict__ fsin,
                                              bf16_t* __restrict__ dst,
                                              int nheads, int stride, float mul) {
  int idx = blockIdx.x * 256 + threadIdx.x;
  int p = idx & 63;
  int h = (idx >> 6) % nheads;
  int bs = idx / (64 * nheads);
  int s = bs & (S_ - 1);
  int b = bs >> 11;
  size_t off = (size_t)bs * stride + h * HD_ + 2 * p;
  bf16x2 ab = *(const bf16x2*)(s1 + off);
  float a = (float)ab[0], bb = (float)ab[1];
  if (s2) {
    bf16x2 ab2 = *(const bf16x2*)(s2 + off);
    a += (float)ab2[0]; bb += (float)ab2[1];
  }
  float c = fcos[s * 64 + p], sn = fsin[s * 64 + p];
  bf16x2 o = { (bf16_t)((a * c - bb * sn) * mul), (bf16_t)((a * sn + bb * c) * mul) };
  *(bf16x2*)(dst + ((((size_t)b * nheads + h) * S_ + s) * HD_) + 2 * p) = o;
}

// ---------------- V transpose from KV parts: -> vt[B][NKV][HD][S] -------------
__global__ __launch_bounds__(256) void k_vtrans(const bf16_t* __restrict__ pA,
                                                const bf16_t* __restrict__ pB,
                                                bf16_t* __restrict__ vtr) {
  __shared__ bf16_t tile[32][33];
  int s0 = blockIdx.x * 32, d0 = blockIdx.y * 32, z = blockIdx.z;  // z = b*NKV+kvh
  int b = z >> 3, kvh = z & 7;
  int tx = threadIdx.x, ty = threadIdx.y;
#pragma unroll
  for (int i = 0; i < 4; i++) {
    size_t off = (size_t)(b * S_ + s0 + ty + 8*i) * 2048 + 1024 + kvh * HD_ + d0 + tx;
    tile[ty + 8*i][tx] = (bf16_t)((float)pA[off] + (float)pB[off]);
  }
  __syncthreads();
#pragma unroll
  for (int i = 0; i < 4; i++)
    vtr[((size_t)z * HD_ + d0 + ty + 8*i) * S_ + s0 + tx] = tile[tx][ty + 8*i];
}

// ---------------- Flash attention: 32x32x16 MFMA, in-register softmax ---------
// grid (S/128, NH, B), 256 thr (4 waves). Wave w owns 32 q-rows.
// Round-15 changes vs round-14 (conflict fix, 1.756e7 -> target <5e6):
//  - K tile: 256B rows, FULL (r&15)<<4 swizzle -> 32-row reads spread 16 slots.
//  - V tile repacked [64 rows][256B] (two d per row: byte=(d&1)*128+2s),
//    (row&15)<<4 swizzle, staging source decodes (d,s) from inverse-swz slot.
//  - Epilogue transpose: (q&15)<<4 swizzle on writes and read-back.
#define KVBLK 64
#define SM_THR 12.0f
__global__ __launch_bounds__(256, 2) void k_flash(const bf16_t* __restrict__ qr,
                                                  const bf16_t* __restrict__ kr,
                                                  const bf16_t* __restrict__ vt,
                                                  bf16_t* __restrict__ ctx) {
  __shared__ __align__(16) bf16_t Ks[2][KVBLK * HD_];   // 2 x 16 KB [s][d] swz16
  __shared__ __align__(16) bf16_t Vs[2][64 * 128];      // 2 x 16 KB [d>>1][..] swz16
  const int tid = threadIdx.x;
  const int l = tid & 63, w = tid >> 6;
  const int q5 = l & 31, h = l >> 5;
  const int qb = blockIdx.x, hh = blockIdx.y, b = blockIdx.z;
  const int kvh = hh >> 2;   // NREP=4

  const bf16_t* qbase = qr + (((size_t)b * NH_ + hh) * S_ + qb * 128 + w * 32) * HD_;
  const bf16_t* kbase = kr + (((size_t)b * NKV_ + kvh) * S_) * HD_;
  const bf16_t* vbase = vt + (((size_t)b * NKV_ + kvh) * HD_) * S_;

  // Q fragments (B-operand): qf[s]: Q[q5][16s + 8h + 0..7], s=0..7
  bf16x8 qf[8];
#pragma unroll
  for (int s = 0; s < 8; s++)
    qf[s] = LD8(qbase + q5 * HD_ + s * 16 + h * 8);

  f32x16 acco[4];
#pragma unroll
  for (int db = 0; db < 4; db++)
#pragma unroll
    for (int r = 0; r < 16; r++) acco[db][r] = 0.f;
  float mR = -1e30f, lR = 0.f;

  auto stage = [&](int bu, int t) {
    const int kb = t * KVBLK;
    // K: rows 256B, (row&15) swizzle; linear dest + pre-swizzled source col
#pragma unroll
    for (int j = 0; j < 4; j++) {
      int o_ = (tid + 256 * j) * 16;
      int row = o_ >> 8, cb = o_ & 255;
      int scb = cb ^ ((row & 15) << 4);
      gload_lds16(kbase + (size_t)(kb + row) * HD_ + (scb >> 1),
                  &Ks[bu][0] + (o_ >> 1));
    }
    // V: [64 rows][256B], byte=(d&1)*128+2s within row pair, (row&15) swizzle
#pragma unroll
    for (int j = 0; j < 4; j++) {
      int o_ = (tid + 256 * j) * 16;
      int row = o_ >> 8, cb = o_ & 255;
      int sin_ = cb ^ ((row & 15) << 4);
      int d = 2 * row + (sin_ >> 7);
      int s0 = (sin_ & 127) >> 1;
      gload_lds16(vbase + (size_t)d * S_ + kb + s0,
                  &Vs[bu][0] + (o_ >> 1));
    }
  };

  const int nt = S_ / KVBLK;
  stage(0, 0);
  __syncthreads();
  int buf = 0;

  for (int t = 0; t < nt; t++) {
    if (t + 1 < nt) stage(buf ^ 1, t + 1);
    const bf16_t* Kb = &Ks[buf][0];
    const bf16_t* Vb = &Vs[buf][0];

    // QK^T: acc_s[kb] over 8 hd-steps
    f32x16 accs[2];
#pragma unroll
    for (int kb = 0; kb < 2; kb++)
#pragma unroll
      for (int r = 0; r < 16; r++) accs[kb][r] = 0.f;
    __builtin_amdgcn_s_setprio(1);
#pragma unroll
    for (int s = 0; s < 8; s++) {
#pragma unroll
      for (int kb = 0; kb < 2; kb++) {
        int r = kb * 32 + q5;
        int cb = (32 * s + 16 * h) ^ ((r & 15) << 4);
        bf16x8 kf = LD8(Kb + (r << 7) + (cb >> 1));
        accs[kb] = MFMA32(kf, qf[s], accs[kb]);
      }
    }
    __builtin_amdgcn_s_setprio(0);

    // softmax: per-lane scalar stats (lane's 32 scores all belong to q=q5)
    float lm = accs[0][0];
#pragma unroll
    for (int kb = 0; kb < 2; kb++)
#pragma unroll
      for (int r = 0; r < 16; r++)
        if (kb | r) lm = fmaxf(lm, accs[kb][r]);
    if (!__all(lm - mR <= SM_THR)) {     // trigger: tile 0 + rare growth
      float fm = fmaxf(lm, __shfl_xor(lm, 32));
      float mnew = fmaxf(mR, fm);
      float alpha = exp2_fast(mR - mnew);
      mR = mnew;
      lR *= alpha;
#pragma unroll
      for (int db = 0; db < 4; db++)
#pragma unroll
        for (int r = 0; r < 16; r++) acco[db][r] *= alpha;
    }
    // P = 2^(sc-mR); pack + permlane-exchange into PV B-frags
    float psum = 0.f;
    bf16x8 pb[4];
#pragma unroll
    for (int s2 = 0; s2 < 4; s2++) {
      const int kb = s2 >> 1, rb = (s2 & 1) * 8;
      float pv[8];
#pragma unroll
      for (int j = 0; j < 8; j++) {
        pv[j] = exp2_fast(accs[kb][rb + j] - mR);
        psum += pv[j];
      }
      unsigned wlo0 = cvt_pk_bf16(pv[0], pv[1]);
      unsigned wlo1 = cvt_pk_bf16(pv[2], pv[3]);
      unsigned whi0 = cvt_pk_bf16(pv[4], pv[5]);
      unsigned whi1 = cvt_pk_bf16(pv[6], pv[7]);
      asm volatile("v_permlane32_swap_b32 %0, %1" : "+v"(wlo0), "+v"(whi0));
      asm volatile("v_permlane32_swap_b32 %0, %1" : "+v"(wlo1), "+v"(whi1));
      uint32x4 wv = { wlo0, wlo1, whi0, whi1 };
      pb[s2] = __builtin_bit_cast(bf16x8, wv);
    }
    psum += __shfl_xor(psum, 32);
    lR += psum;

    // PV: acc_o[db] += V^T-frag x P-frag (V rows paired: row=rv>>1)
    __builtin_amdgcn_s_setprio(1);
#pragma unroll
    for (int s2 = 0; s2 < 4; s2++) {
#pragma unroll
      for (int db = 0; db < 4; db++) {
        int rv = db * 32 + q5;
        int row = rv >> 1;
        int cb = (((rv & 1) << 7) | (32 * s2 + 16 * h)) ^ ((row & 15) << 4);
        bf16x8 vf = LD8(Vb + (row << 7) + (cb >> 1));
        acco[db] = MFMA32(vf, pb[s2], acco[db]);
      }
    }
    __builtin_amdgcn_s_setprio(0);
    __syncthreads();
    buf ^= 1;
  }

  // epilogue: normalize + transpose O^T[d][q] -> ctx[q][d] via LDS (reuse Ks)
  float inv = 1.0f / lR;
  bf16_t* tb = &Ks[0][0] + w * (32 * 128);   // per-wave [32 q][256B] region
#pragma unroll
  for (int db = 0; db < 4; db++)
#pragma unroll
    for (int rp = 0; rp < 8; rp++) {
      int r = 2 * rp;
      int d0 = (r & 3) + 8 * (r >> 2) + 4 * h + 32 * db;
      unsigned word = cvt_pk_bf16(acco[db][r] * inv, acco[db][r + 1] * inv);
      int cbyte = (d0 * 2) ^ ((q5 & 15) << 4);
      *(unsigned*)((char*)tb + q5 * 256 + cbyte) = word;
    }
  __syncthreads();
#pragma unroll
  for (int it = 0; it < 8; it++) {
    int gid = it * 256 + tid;                 // granule id: 4w x 32q x 16g
    int wv = gid >> 9, rem = gid & 511;
    int qq = rem >> 4, g = rem & 15;
    int cbyte = (g * 16) ^ ((qq & 15) << 4);
    bf16x8 v = LD8((const bf16_t*)((const char*)(&Ks[0][0] + wv * (32 * 128)) + qq * 256 + cbyte));
    int srow = qb * 128 + wv * 32 + qq;
    *(bf16x8*)(ctx + ((size_t)(b * S_ + srow)) * D_ + hh * HD_ + g * 8) = v;
  }
}

// ---------------- launch ----------------
extern "C" void kernel_launch(void* const* d_in, const int* in_sizes, int n_in,
                              void* d_out, int out_size, void* d_ws, size_t ws_size,
                              hipStream_t stream) {
  const float* x    = (const float*)d_in[0];
  const float* wq   = (const float*)d_in[1];
  const float* wk   = (const float*)d_in[2];
  const float* wv   = (const float*)d_in[3];
  const float* wo   = (const float*)d_in[4];
  const float* fcos = (const float*)d_in[5];
  const float* fsin = (const float*)d_in[6];
  float* out = (float*)d_out;

  // workspace layout (160 MB, aliased) — see round-13 notes
  const size_t MB = 1u << 20;
  char* p = (char*)d_ws;
  bf16_t* xb    = (bf16_t*)p;
  bf16_t* wqkvt = (bf16_t*)(p + 32 * MB);
  bf16_t* wot   = (bf16_t*)(p + 80 * MB);
  bf16_t* qc    = (bf16_t*)(p + 112 * MB);
  bf16_t* partA = (bf16_t*)(p + 144 * MB);
  bf16_t* partB = wot;
  bf16_t* qrope = xb;
  bf16_t* krope = wqkvt;
  bf16_t* vtr   = wqkvt + (size_t)BS_ * NKV_ * HD_;
  bf16_t* ctx   = qc;

  // Q pre-scale: log2(e) / sqrt(HD)  (scores land in log2 domain)
  const float QSCALE = (float)(0.08838834764831845 * 1.4426950408889634);

  dim3 tb(32, 8);
  // 1. x -> bf16
  k_cvt<<<BS_ * D_ / 1024, 256, 0, stream>>>((const float4*)x, (bf16x4*)xb, BS_ * D_ / 4);
  // 2. transpose+convert q/k/v weights (wo later — its slot holds partB)
  k_transpose_cvt<<<dim3(D_ / 32, D_ / 32), tb, 0, stream>>>(wq, wqkvt, D_, D_);
  k_transpose_cvt<<<dim3(32, D_ / 32), tb, 0, stream>>>(wk, wqkvt + (size_t)D_ * D_, D_, NKV_ * HD_);
  k_transpose_cvt<<<dim3(32, D_ / 32), tb, 0, stream>>>(wv, wqkvt + (size_t)(D_ + NKV_ * HD_) * D_, D_, NKV_ * HD_);
  // 3a. Q projection: NF=4, 16x16 = 256 blocks = 1 clean round
  k_gemm8p<bf16_t><<<dim3(BS_ / 256, D_ / 256, 1), 512, 0, stream>>>(
      xb, wqkvt, qc, BS_, D_, D_, D_, 0);
  // 3b. KV projection, split-K=2: grid (16,8,2) = 256 blocks = 1 clean round
  k_gemm8p<bf16_t><<<dim3(BS_ / 256, 2048 / 256, 2), 512, 0, stream>>>(
      xb, wqkvt + (size_t)D_ * D_, partA, BS_, 2048, D_, 2048,
      (long long)(partB - partA));
  // 4. RoPE + reorder; K/V sum the two split-K parts
  k_rope<<<BS_ * NH_ * 64 / 256, 256, 0, stream>>>(qc, (const bf16_t*)nullptr,
      fcos, fsin, qrope, NH_, D_, QSCALE);
  k_rope<<<BS_ * NKV_ * 64 / 256, 256, 0, stream>>>(partA, partB,
      fcos, fsin, krope, NKV_, 2048, 1.0f);
  k_vtrans<<<dim3(S_ / 32, HD_ / 32, B_ * NKV_), tb, 0, stream>>>(partA, partB, vtr);
  // 5. transpose wo (partB now dead)
  k_transpose_cvt<<<dim3(D_ / 32, D_ / 32), tb, 0, stream>>>(wo, wot, D_, D_);
  // 6. flash attention (32x32 MFMA, full-width swizzles)
  k_flash<<<dim3(S_ / 128, NH_, B_), 256, 0, stream>>>(qrope, krope, vtr, ctx);
  // 7. output projection -> f32 out: 256 blocks = 1 round
  k_gemm8p<float><<<dim3(BS_ / 256, D_ / 256, 1), 512, 0, stream>>>(
      ctx, wot, out, BS_, D_, D_, D_, 0);
}